// Round 1
// baseline (19897.050 us; speedup 1.0000x reference)
//
#include <hip/hip_runtime.h>
#include <cstdint>

#define B_ 8
#define S_ 1024
#define D_ 512
#define H_ 8
#define HD_ 64
#define FF_ 2048
#define STEPS_ 64
#define CAP_ (S_ + STEPS_)
#define EPS_ 1e-5f

// ---------------------------------------------------------------------------
// GEMM NT: C[M,N] = A[M,K] * B[N,K]^T + bias  (+optional residual, relu)
// mode 0: plain store C[m*N+n]
// mode 1: QKV routing: n<512 -> q_buf, n<1024 -> k_cache, else v_cache
// ---------------------------------------------------------------------------
__global__ __launch_bounds__(256) void gemm_nt(
    const float* __restrict__ A, const float* __restrict__ Bm,
    const float* __restrict__ bias, const float* __restrict__ res,
    float* __restrict__ C, float* __restrict__ kc, float* __restrict__ vc,
    int M, int N, int K, int mode, int relu)
{
  __shared__ float As[16][68];
  __shared__ float Bs[16][68];
  const int tid = threadIdx.x;
  const int tx = tid & 15, ty = tid >> 4;
  const int bm = blockIdx.x * 64, bn = blockIdx.y * 64;
  const int lrow = tid >> 2;          // 0..63
  const int lc4  = (tid & 3) * 4;     // 0,4,8,12
  const float* Ab = A  + (size_t)(bm + lrow) * K + lc4;
  const float* Bb = Bm + (size_t)(bn + lrow) * K + lc4;
  float acc[4][4] = {};

  for (int k0 = 0; k0 < K; k0 += 16) {
    float4 av = *(const float4*)(Ab + k0);
    float4 bv = *(const float4*)(Bb + k0);
    __syncthreads();
    As[lc4 + 0][lrow] = av.x; As[lc4 + 1][lrow] = av.y;
    As[lc4 + 2][lrow] = av.z; As[lc4 + 3][lrow] = av.w;
    Bs[lc4 + 0][lrow] = bv.x; Bs[lc4 + 1][lrow] = bv.y;
    Bs[lc4 + 2][lrow] = bv.z; Bs[lc4 + 3][lrow] = bv.w;
    __syncthreads();
#pragma unroll
    for (int kk = 0; kk < 16; ++kk) {
      float4 a  = *(const float4*)&As[kk][ty * 4];
      float4 bq = *(const float4*)&Bs[kk][tx * 4];
      float ar[4] = {a.x, a.y, a.z, a.w};
      float br[4] = {bq.x, bq.y, bq.z, bq.w};
#pragma unroll
      for (int i = 0; i < 4; ++i)
#pragma unroll
        for (int j = 0; j < 4; ++j)
          acc[i][j] = fmaf(ar[i], br[j], acc[i][j]);
    }
  }

#pragma unroll
  for (int i = 0; i < 4; ++i) {
    int m = bm + ty * 4 + i;
#pragma unroll
    for (int j = 0; j < 4; ++j) {
      int n = bn + tx * 4 + j;
      float v = acc[i][j] + bias[n];
      if (relu) v = fmaxf(v, 0.f);
      if (res)  v += res[(size_t)m * N + n];
      if (mode == 0) {
        C[(size_t)m * N + n] = v;
      } else {
        int b = m >> 10, s = m & 1023;
        if (n < 512) {
          C[((size_t)m << 9) + n] = v;                      // q_buf [8192,512]
        } else {
          float* dst = (n < 1024) ? kc : vc;
          dst[((size_t)(b * CAP_ + s) << 9) + (n & 511)] = v;
        }
      }
    }
  }
}

// ---------------------------------------------------------------------------
// Prefill causal attention: one wave (64 lanes = head dims) per (b,h,s) row,
// online softmax streaming over t = 0..s.
// ---------------------------------------------------------------------------
__global__ __launch_bounds__(64) void attn_prefill(
    const float* __restrict__ q_buf, const float* __restrict__ kc,
    const float* __restrict__ vc, float* __restrict__ o)
{
  const int idx = blockIdx.x;
  const int s = idx & 1023;
  const int h = (idx >> 10) & 7;
  const int b = idx >> 13;
  const int lane = threadIdx.x;

  const float q = q_buf[((size_t)((b << 10) + s) << 9) + h * 64 + lane] * 0.125f;
  const float* kb = kc + ((size_t)(b * CAP_) << 9) + h * 64 + lane;
  const float* vb = vc + ((size_t)(b * CAP_) << 9) + h * 64 + lane;

  float m = -1e30f, l = 0.f, acc = 0.f;
  for (int t = 0; t <= s; ++t) {
    float p = q * kb[(size_t)t * 512];
#pragma unroll
    for (int off = 32; off; off >>= 1) p += __shfl_xor(p, off, 64);
    float vv = vb[(size_t)t * 512];
    if (p <= m) {                       // uniform branch: p same on all lanes
      float e = __expf(p - m);
      acc += e * vv; l += e;
    } else {
      float c = __expf(m - p);
      acc = acc * c + vv; l = l * c + 1.f; m = p;
    }
  }
  o[((size_t)((b << 10) + s) << 9) + h * 64 + lane] = acc / l;
}

// ---------------------------------------------------------------------------
// Row LayerNorm over D=512, 256 threads x 2 elems.
// outmode 0: out[m*512+d]; outmode 1: out[(b*1088+s)*512+d] (prefill -> d_out)
// ---------------------------------------------------------------------------
__global__ __launch_bounds__(256) void ln_rows(
    const float* __restrict__ in, float* __restrict__ out,
    const float* __restrict__ w, const float* __restrict__ bb, int outmode)
{
  __shared__ float s1[256], s2[256];
  const int m = blockIdx.x, tid = threadIdx.x;
  const float* row = in + ((size_t)m << 9);
  float x0 = row[tid], x1 = row[tid + 256];
  s1[tid] = x0 + x1;
  s2[tid] = x0 * x0 + x1 * x1;
  __syncthreads();
  for (int st = 128; st > 0; st >>= 1) {
    if (tid < st) { s1[tid] += s1[tid + st]; s2[tid] += s2[tid + st]; }
    __syncthreads();
  }
  float mu  = s1[0] * (1.f / 512.f);
  float var = s2[0] * (1.f / 512.f) - mu * mu;
  float inv = rsqrtf(var + EPS_);
  size_t ob;
  if (outmode == 0) ob = (size_t)m << 9;
  else { int b = m >> 10, s = m & 1023; ob = (size_t)(b * CAP_ + s) << 9; }
  out[ob + tid]       = (x0 - mu) * inv * w[tid]       + bb[tid];
  out[ob + tid + 256] = (x1 - mu) * inv * w[tid + 256] + bb[tid + 256];
}

// ---------------------------------------------------------------------------
// Decode kernels (per step, B=8 tokens)
// ---------------------------------------------------------------------------
__global__ __launch_bounds__(256) void dec_qkv(
    const float* __restrict__ xt, const float* __restrict__ qw,
    const float* __restrict__ qb, float* __restrict__ qt,
    float* __restrict__ kc, float* __restrict__ vc, int step)
{
  __shared__ float xs[512];
  const int b = blockIdx.y;
  const int tid = threadIdx.x;
  const int n = blockIdx.x * 256 + tid;
  xs[tid]       = xt[b * 512 + tid];
  xs[tid + 256] = xt[b * 512 + 256 + tid];
  __syncthreads();
  const float4* w4 = (const float4*)(qw + (size_t)n * 512);
  float acc = qb[n];
#pragma unroll 8
  for (int i = 0; i < 128; ++i) {
    float4 wv = w4[i];
    float4 xv = *(const float4*)&xs[i * 4];
    acc += xv.x * wv.x + xv.y * wv.y + xv.z * wv.z + xv.w * wv.w;
  }
  if (n < 512) {
    qt[b * 512 + n] = acc;
  } else {
    float* dst = (n < 1024) ? kc : vc;
    dst[((size_t)(b * CAP_ + S_ + step) << 9) + (n & 511)] = acc;
  }
}

__global__ __launch_bounds__(256) void dec_attn(
    const float* __restrict__ qt, const float* __restrict__ kc,
    const float* __restrict__ vc, float* __restrict__ at, int kv_len)
{
  __shared__ float qs[64];
  __shared__ float sc[CAP_];
  __shared__ float red[256];
  const int b = blockIdx.x >> 3, h = blockIdx.x & 7;
  const int tid = threadIdx.x;
  if (tid < 64) qs[tid] = qt[b * 512 + h * 64 + tid] * 0.125f;
  __syncthreads();

  for (int pos = tid; pos < kv_len; pos += 256) {
    const float4* k4 = (const float4*)(kc + ((size_t)(b * CAP_ + pos) << 9) + h * 64);
    const float4* q4 = (const float4*)qs;
    float a = 0.f;
#pragma unroll
    for (int i = 0; i < 16; ++i) {
      float4 kv = k4[i]; float4 qv = q4[i];
      a += qv.x * kv.x + qv.y * kv.y + qv.z * kv.z + qv.w * kv.w;
    }
    sc[pos] = a;
  }
  __syncthreads();

  float mx = -1e30f;
  for (int pos = tid; pos < kv_len; pos += 256) mx = fmaxf(mx, sc[pos]);
  red[tid] = mx; __syncthreads();
  for (int st = 128; st > 0; st >>= 1) {
    if (tid < st) red[tid] = fmaxf(red[tid], red[tid + st]);
    __syncthreads();
  }
  float M = red[0]; __syncthreads();

  float sm = 0.f;
  for (int pos = tid; pos < kv_len; pos += 256) {
    float e = __expf(sc[pos] - M);
    sc[pos] = e; sm += e;
  }
  red[tid] = sm; __syncthreads();
  for (int st = 128; st > 0; st >>= 1) {
    if (tid < st) red[tid] += red[tid + st];
    __syncthreads();
  }
  float inv = 1.f / red[0]; __syncthreads();

  const int d = tid & 63, ch = tid >> 6;      // 4 chunks
  float o = 0.f;
  for (int t2 = ch; t2 < kv_len; t2 += 4)
    o += sc[t2] * vc[((size_t)(b * CAP_ + t2) << 9) + h * 64 + d];
  red[tid] = o; __syncthreads();
  if (ch == 0)
    at[b * 512 + h * 64 + d] = (red[d] + red[64 + d] + red[128 + d] + red[192 + d]) * inv;
}

__global__ __launch_bounds__(512) void dec_proj_ln(
    const float* __restrict__ at, const float* __restrict__ xt,
    const float* __restrict__ ow, const float* __restrict__ ob,
    const float* __restrict__ lw, const float* __restrict__ lb,
    float* __restrict__ hd)
{
  __shared__ float as[512];
  __shared__ float s1[512], s2[512];
  const int b = blockIdx.x, e = threadIdx.x;
  as[e] = at[b * 512 + e];
  __syncthreads();
  const float4* w4 = (const float4*)(ow + (size_t)e * 512);
  float acc = ob[e];
#pragma unroll 8
  for (int i = 0; i < 128; ++i) {
    float4 wv = w4[i];
    float4 av = *(const float4*)&as[i * 4];
    acc += av.x * wv.x + av.y * wv.y + av.z * wv.z + av.w * wv.w;
  }
  float val = xt[b * 512 + e] + acc;
  s1[e] = val; s2[e] = val * val;
  __syncthreads();
  for (int st = 256; st > 0; st >>= 1) {
    if (e < st) { s1[e] += s1[e + st]; s2[e] += s2[e + st]; }
    __syncthreads();
  }
  float mu  = s1[0] * (1.f / 512.f);
  float var = s2[0] * (1.f / 512.f) - mu * mu;
  float inv = rsqrtf(var + EPS_);
  hd[b * 512 + e] = (val - mu) * inv * lw[e] + lb[e];
}

__global__ __launch_bounds__(256) void dec_mlp1(
    const float* __restrict__ hd, const float* __restrict__ w1,
    const float* __restrict__ b1, float* __restrict__ hid)
{
  __shared__ float xs[512];
  const int b = blockIdx.y;
  const int tid = threadIdx.x;
  const int f = blockIdx.x * 256 + tid;
  xs[tid]       = hd[b * 512 + tid];
  xs[tid + 256] = hd[b * 512 + 256 + tid];
  __syncthreads();
  const float4* w4 = (const float4*)(w1 + (size_t)f * 512);
  float acc = b1[f];
#pragma unroll 8
  for (int i = 0; i < 128; ++i) {
    float4 wv = w4[i];
    float4 xv = *(const float4*)&xs[i * 4];
    acc += xv.x * wv.x + xv.y * wv.y + xv.z * wv.z + xv.w * wv.w;
  }
  hid[b * 2048 + f] = fmaxf(acc, 0.f);
}

__global__ __launch_bounds__(512) void dec_mlp2(
    const float* __restrict__ hid, const float* __restrict__ hd,
    const float* __restrict__ w2, const float* __restrict__ b2,
    const float* __restrict__ lw, const float* __restrict__ lb,
    float* __restrict__ out, int step)
{
  __shared__ float hs[2048];
  __shared__ float s1[512], s2[512];
  const int b = blockIdx.x, e = threadIdx.x;
  ((float4*)hs)[e] = ((const float4*)(hid + (size_t)b * 2048))[e];
  __syncthreads();
  const float4* w4 = (const float4*)(w2 + (size_t)e * 2048);
  float acc = b2[e];
#pragma unroll 4
  for (int i = 0; i < 512; ++i) {
    float4 wv = w4[i];
    float4 hv = *(const float4*)&hs[i * 4];
    acc += hv.x * wv.x + hv.y * wv.y + hv.z * wv.z + hv.w * wv.w;
  }
  float val = hd[b * 512 + e] + acc;
  s1[e] = val; s2[e] = val * val;
  __syncthreads();
  for (int st = 256; st > 0; st >>= 1) {
    if (e < st) { s1[e] += s1[e + st]; s2[e] += s2[e + st]; }
    __syncthreads();
  }
  float mu  = s1[0] * (1.f / 512.f);
  float var = s2[0] * (1.f / 512.f) - mu * mu;
  float inv = rsqrtf(var + EPS_);
  out[((size_t)(b * CAP_ + S_ + step) << 9) + e] = (val - mu) * inv * lw[e] + lb[e];
}

// ---------------------------------------------------------------------------
extern "C" void kernel_launch(void* const* d_in, const int* in_sizes, int n_in,
                              void* d_out, int out_size, void* d_ws, size_t ws_size,
                              hipStream_t stream)
{
  const float* x     = (const float*)d_in[0];
  const float* dx    = (const float*)d_in[1];
  // d_in[2] = causal mask: implied structurally, unused
  const float* qkv_w = (const float*)d_in[3];
  const float* qkv_b = (const float*)d_in[4];
  const float* out_w = (const float*)d_in[5];
  const float* out_b = (const float*)d_in[6];
  const float* w1    = (const float*)d_in[7];
  const float* b1    = (const float*)d_in[8];
  const float* w2    = (const float*)d_in[9];
  const float* b2    = (const float*)d_in[10];
  const float* ln1w  = (const float*)d_in[11];
  const float* ln1b  = (const float*)d_in[12];
  const float* ln2w  = (const float*)d_in[13];
  const float* ln2b  = (const float*)d_in[14];
  float* out = (float*)d_out;

  float* ws = (float*)d_ws;
  size_t o = 0;
  float* q_buf  = ws + o; o += (size_t)8192 * 512;   // 16.8 MB
  float* attn_o = ws + o; o += (size_t)8192 * 512;   // 16.8 MB
  float* h1     = ws + o; o += (size_t)8192 * 512;   // 16.8 MB
  float* hidden = ws + o; o += (size_t)8192 * 2048;  // 67 MB
  float* kc     = ws + o; o += (size_t)B_ * CAP_ * 512;  // 17.8 MB
  float* vc     = ws + o; o += (size_t)B_ * CAP_ * 512;  // 17.8 MB
  float* q_t    = ws + o; o += 8 * 512;
  float* attn_t = ws + o; o += 8 * 512;
  float* h_t    = ws + o; o += 8 * 512;
  float* hid_t  = ws + o; o += 8 * 2048;

  // ---- prefill ----
  gemm_nt<<<dim3(128, 24), 256, 0, stream>>>(x, qkv_w, qkv_b, nullptr,
                                             q_buf, kc, vc, 8192, 1536, 512, 1, 0);
  attn_prefill<<<dim3(65536), 64, 0, stream>>>(q_buf, kc, vc, attn_o);
  gemm_nt<<<dim3(128, 8), 256, 0, stream>>>(attn_o, out_w, out_b, x,
                                            h1, nullptr, nullptr, 8192, 512, 512, 0, 0);
  ln_rows<<<dim3(8192), 256, 0, stream>>>(h1, h1, ln1w, ln1b, 0);
  gemm_nt<<<dim3(128, 32), 256, 0, stream>>>(h1, w1, b1, nullptr,
                                             hidden, nullptr, nullptr, 8192, 2048, 512, 0, 1);
  gemm_nt<<<dim3(128, 8), 256, 0, stream>>>(hidden, w2, b2, h1,
                                            q_buf, nullptr, nullptr, 8192, 512, 2048, 0, 0);
  ln_rows<<<dim3(8192), 256, 0, stream>>>(q_buf, out, ln2w, ln2b, 1);

  // ---- decode: 64 sequential steps ----
  for (int t = 0; t < STEPS_; ++t) {
    const float* xt = dx + (size_t)t * B_ * 512;
    dec_qkv<<<dim3(6, 8), 256, 0, stream>>>(xt, qkv_w, qkv_b, q_t, kc, vc, t);
    dec_attn<<<dim3(64), 256, 0, stream>>>(q_t, kc, vc, attn_t, S_ + t + 1);
    dec_proj_ln<<<dim3(8), 512, 0, stream>>>(attn_t, xt, out_w, out_b, ln1w, ln1b, h_t);
    dec_mlp1<<<dim3(8, 8), 256, 0, stream>>>(h_t, w1, b1, hid_t);
    dec_mlp2<<<dim3(8), 512, 0, stream>>>(hid_t, h_t, w2, b2, ln2w, ln2b, out, t);
  }
}

// Round 2
// 8344.724 us; speedup vs baseline: 2.3844x; 2.3844x over previous
//
#include <hip/hip_runtime.h>
#include <cstdint>

#define B_ 8
#define S_ 1024
#define D_ 512
#define FF_ 2048
#define STEPS_ 64
#define CAP_ 1088
#define EPS_ 1e-5f

using bf8   = __attribute__((ext_vector_type(8))) short;
using f32x4 = __attribute__((ext_vector_type(4))) float;

__device__ __forceinline__ unsigned short f2bf(float f) {
  unsigned u = __float_as_uint(f);
  u += 0x7fffu + ((u >> 16) & 1);
  return (unsigned short)(u >> 16);
}

typedef const __attribute__((address_space(1))) void* gp1;
typedef __attribute__((address_space(3))) void* lp3;
__device__ __forceinline__ void async16(const void* g, void* l) {
  __builtin_amdgcn_global_load_lds((gp1)g, (lp3)l, 16, 0, 0);
}

// ---------------------------------------------------------------------------
// fp32 -> bf16 conversion (4 elems/thread)
// ---------------------------------------------------------------------------
__global__ __launch_bounds__(256) void cvt_bf16(const float* __restrict__ in,
                                                unsigned short* __restrict__ out,
                                                int n4) {
  int i = blockIdx.x * 256 + threadIdx.x;
  if (i >= n4) return;
  float4 v = ((const float4*)in)[i];
  ushort4 o;
  o.x = f2bf(v.x); o.y = f2bf(v.y); o.z = f2bf(v.z); o.w = f2bf(v.w);
  ((ushort4*)out)[i] = o;
}

// ---------------------------------------------------------------------------
// bf16 MFMA GEMM NT: C[M,N] = A[M,K] * B[N,K]^T + bias (+res, relu)
// 128x128 tile, BK=64, 4 waves (2x2 of 64x64), 16x16x32 MFMA.
// global_load_lds(16B) into XOR-swizzled LDS (chunk ^= row&7).
// mode 0: fp32 C; mode 1: QKV route fp32 (q/kc/vc); mode 2: bf16 C.
// ---------------------------------------------------------------------------
__global__ __launch_bounds__(256) void mfma_gemm(
    const unsigned short* __restrict__ A, const unsigned short* __restrict__ Bw,
    const float* __restrict__ bias, const float* __restrict__ res,
    float* __restrict__ Cf, float* __restrict__ kcv, float* __restrict__ vcv,
    unsigned short* __restrict__ Cb,
    int M, int N, int K, int mode, int relu)
{
  __shared__ unsigned short Als[128 * 64];
  __shared__ unsigned short Bls[128 * 64];
  const int tid  = threadIdx.x;
  const int lane = tid & 63, w = tid >> 6;
  const int bm = blockIdx.x * 128, bn = blockIdx.y * 128;
  const int wm = (w >> 1) * 64, wn = (w & 1) * 64;

  f32x4 acc[4][4] = {};

  const int so = tid * 16;   // byte offset of this thread's 16B in each 4KB chunk
  for (int k0 = 0; k0 < K; k0 += 64) {
#pragma unroll
    for (int it = 0; it < 4; ++it) {
      int o   = it * 4096 + so;
      int row = o >> 7;             // 128 B per LDS row (64 bf16)
      int ch  = (o >> 4) & 7;
      int sch = ch ^ (row & 7);     // inverse-swizzled global source
      async16(A  + (size_t)(bm + row) * K + k0 + sch * 8, (char*)Als + o);
      async16(Bw + (size_t)(bn + row) * K + k0 + sch * 8, (char*)Bls + o);
    }
    __syncthreads();
#pragma unroll
    for (int ks = 0; ks < 2; ++ks) {
      bf8 af[4], bfr[4];
#pragma unroll
      for (int m = 0; m < 4; ++m) {
        int row = wm + m * 16 + (lane & 15);
        int ch  = ks * 4 + (lane >> 4);
        af[m] = *(const bf8*)((const char*)Als + row * 128 + ((ch ^ (row & 7)) * 16));
      }
#pragma unroll
      for (int n = 0; n < 4; ++n) {
        int row = wn + n * 16 + (lane & 15);
        int ch  = ks * 4 + (lane >> 4);
        bfr[n] = *(const bf8*)((const char*)Bls + row * 128 + ((ch ^ (row & 7)) * 16));
      }
#pragma unroll
      for (int m = 0; m < 4; ++m)
#pragma unroll
        for (int n = 0; n < 4; ++n)
          acc[m][n] = __builtin_amdgcn_mfma_f32_16x16x32_bf16(af[m], bfr[n], acc[m][n], 0, 0, 0);
    }
    __syncthreads();
  }

  // epilogue: D row = (lane>>4)*4 + r, col = lane&15  [m89-verified layout]
#pragma unroll
  for (int m = 0; m < 4; ++m) {
#pragma unroll
    for (int n = 0; n < 4; ++n) {
      int col = bn + wn + n * 16 + (lane & 15);
      float bcol = bias[col];
#pragma unroll
      for (int r = 0; r < 4; ++r) {
        int row = bm + wm + m * 16 + (lane >> 4) * 4 + r;
        float v = acc[m][n][r] + bcol;
        if (relu) v = fmaxf(v, 0.f);
        if (res)  v += res[(size_t)row * N + col];
        if (mode == 0) {
          Cf[(size_t)row * N + col] = v;
        } else if (mode == 1) {
          int bb = row >> 10, s = row & 1023;
          if (col < 512) {
            Cf[((size_t)row << 9) + col] = v;
          } else {
            float* dst = (col < 1024) ? kcv : vcv;
            dst[(((size_t)(bb * CAP_ + s)) << 9) + (col & 511)] = v;
          }
        } else {
          Cb[(size_t)row * N + col] = f2bf(v);
        }
      }
    }
  }
}

// ---------------------------------------------------------------------------
// Prefill attention: 64x64 tiles, fp32 vector math, online softmax.
// Block 256 thr = (b,h,stile). Qls/Kls [d][r], V [r][d] (shares Kls buffer),
// P^T staged in St[c][r]. Microtile 4x4 per thread (ty=rows, tx=cols).
// ---------------------------------------------------------------------------
__global__ __launch_bounds__(256) void attn_tile(
    const float* __restrict__ q_buf, const float* __restrict__ kc,
    const float* __restrict__ vc, unsigned short* __restrict__ ob)
{
  __shared__ float Qls[64][64];
  __shared__ float KV[64][64];
  __shared__ float St[64][68];
  const int st = blockIdx.x, bh = blockIdx.y;
  const int b = bh >> 3, h = bh & 7;
  const int tid = threadIdx.x;
  const int tx = tid & 15, ty = tid >> 4;
  const int s0 = st * 64;
  const size_t bbase = (size_t)b * CAP_ * 512;

  { // stage Q (scaled by 1/sqrt(64)) transposed -> Qls[d][r]
    const int row = tid & 63, c0 = tid >> 6;
    const float* qr = q_buf + (((size_t)(b << 10) + s0 + row) << 9) + h * 64;
#pragma unroll
    for (int i = 0; i < 4; ++i) {
      int dc = c0 + i * 4;
      float4 v = *(const float4*)(qr + dc * 4);
      Qls[dc * 4 + 0][row] = v.x * 0.125f;
      Qls[dc * 4 + 1][row] = v.y * 0.125f;
      Qls[dc * 4 + 2][row] = v.z * 0.125f;
      Qls[dc * 4 + 3][row] = v.w * 0.125f;
    }
  }

  float m_[4], l_[4], o_[4][4];
#pragma unroll
  for (int i = 0; i < 4; ++i) {
    m_[i] = -1e30f; l_[i] = 0.f;
#pragma unroll
    for (int j = 0; j < 4; ++j) o_[i][j] = 0.f;
  }

  for (int t0 = 0; t0 <= s0; t0 += 64) {
    __syncthreads();               // prev PV done with KV & St
    { // stage K transposed -> KV[d][r]
      const int row = tid & 63, c0 = tid >> 6;
      const float* kr = kc + bbase + (((size_t)(t0 + row)) << 9) + h * 64;
#pragma unroll
      for (int i = 0; i < 4; ++i) {
        int dc = c0 + i * 4;
        float4 v = *(const float4*)(kr + dc * 4);
        KV[dc * 4 + 0][row] = v.x; KV[dc * 4 + 1][row] = v.y;
        KV[dc * 4 + 2][row] = v.z; KV[dc * 4 + 3][row] = v.w;
      }
    }
    __syncthreads();

    float p[4][4];
#pragma unroll
    for (int i = 0; i < 4; ++i)
#pragma unroll
      for (int j = 0; j < 4; ++j) p[i][j] = 0.f;
#pragma unroll 4
    for (int d = 0; d < 64; ++d) {
      float4 qv = *(const float4*)&Qls[d][ty * 4];
      float4 kv = *(const float4*)&KV[d][tx * 4];
      float qa[4] = {qv.x, qv.y, qv.z, qv.w};
      float ka[4] = {kv.x, kv.y, kv.z, kv.w};
#pragma unroll
      for (int i = 0; i < 4; ++i)
#pragma unroll
        for (int j = 0; j < 4; ++j) p[i][j] = fmaf(qa[i], ka[j], p[i][j]);
    }
    if (t0 == s0) {                // causal mask on diagonal tile
#pragma unroll
      for (int i = 0; i < 4; ++i) {
        int rg = ty * 4 + i;
#pragma unroll
        for (int j = 0; j < 4; ++j)
          if (tx * 4 + j > rg) p[i][j] = -1e30f;
      }
    }
    // online softmax; row stats reduced across the 16-lane tx group
#pragma unroll
    for (int i = 0; i < 4; ++i) {
      float rm = fmaxf(fmaxf(p[i][0], p[i][1]), fmaxf(p[i][2], p[i][3]));
#pragma unroll
      for (int off = 1; off < 16; off <<= 1) rm = fmaxf(rm, __shfl_xor(rm, off, 64));
      float mn = fmaxf(m_[i], rm);
      float f  = __expf(m_[i] - mn);
      float rs = 0.f;
#pragma unroll
      for (int j = 0; j < 4; ++j) { p[i][j] = __expf(p[i][j] - mn); rs += p[i][j]; }
#pragma unroll
      for (int off = 1; off < 16; off <<= 1) rs += __shfl_xor(rs, off, 64);
      l_[i] = l_[i] * f + rs;
      m_[i] = mn;
#pragma unroll
      for (int j = 0; j < 4; ++j) o_[i][j] *= f;
    }
    // write P^T -> St[c][r] (float4 along r)
#pragma unroll
    for (int j = 0; j < 4; ++j) {
      float4 col = make_float4(p[0][j], p[1][j], p[2][j], p[3][j]);
      *(float4*)&St[tx * 4 + j][ty * 4] = col;
    }
    __syncthreads();               // K reads done + St visible
    { // stage V natural -> KV[r][d]
      const int c = tid & 15, r4 = tid >> 4;
#pragma unroll
      for (int i = 0; i < 4; ++i) {
        int row = r4 + i * 16;
        float4 v = *(const float4*)(vc + bbase + (((size_t)(t0 + row)) << 9) + h * 64 + c * 4);
        *(float4*)&KV[row][c * 4] = v;
      }
    }
    __syncthreads();
    // PV
#pragma unroll 4
    for (int k = 0; k < 64; ++k) {
      float4 pv = *(const float4*)&St[k][ty * 4];
      float4 vv = *(const float4*)&KV[k][tx * 4];
      float pa[4] = {pv.x, pv.y, pv.z, pv.w};
      float va[4] = {vv.x, vv.y, vv.z, vv.w};
#pragma unroll
      for (int i = 0; i < 4; ++i)
#pragma unroll
        for (int j = 0; j < 4; ++j) o_[i][j] = fmaf(pa[i], va[j], o_[i][j]);
    }
  }
  // finalize -> bf16 out
#pragma unroll
  for (int i = 0; i < 4; ++i) {
    float inv = 1.f / l_[i];
    ushort4 pk;
    pk.x = f2bf(o_[i][0] * inv); pk.y = f2bf(o_[i][1] * inv);
    pk.z = f2bf(o_[i][2] * inv); pk.w = f2bf(o_[i][3] * inv);
    *(ushort4*)(ob + (((size_t)(b << 10) + s0 + ty * 4 + i) << 9) + h * 64 + tx * 4) = pk;
  }
}

// ---------------------------------------------------------------------------
// Row LayerNorm over D=512. outmode 0: outf[m*512] (+opt bf16 copy);
// 1: prefill strided d_out; 2: decode strided d_out (m = b).
// ---------------------------------------------------------------------------
__global__ __launch_bounds__(256) void ln_rows(
    const float* __restrict__ in, float* __restrict__ outf,
    unsigned short* __restrict__ outb,
    const float* __restrict__ w, const float* __restrict__ bb,
    int outmode, int step)
{
  __shared__ float s1[256], s2[256];
  const int m = blockIdx.x, tid = threadIdx.x;
  const float* row = in + ((size_t)m << 9);
  float x0 = row[tid], x1 = row[tid + 256];
  s1[tid] = x0 + x1;
  s2[tid] = x0 * x0 + x1 * x1;
  __syncthreads();
  for (int st = 128; st > 0; st >>= 1) {
    if (tid < st) { s1[tid] += s1[tid + st]; s2[tid] += s2[tid + st]; }
    __syncthreads();
  }
  float mu  = s1[0] * (1.f / 512.f);
  float var = s2[0] * (1.f / 512.f) - mu * mu;
  float inv = rsqrtf(var + EPS_);
  size_t ob;
  if (outmode == 0)      ob = (size_t)m << 9;
  else if (outmode == 1) { int b = m >> 10, s = m & 1023; ob = ((size_t)(b * CAP_ + s)) << 9; }
  else                   ob = ((size_t)(m * CAP_ + S_ + step)) << 9;
  float y0 = (x0 - mu) * inv * w[tid] + bb[tid];
  float y1 = (x1 - mu) * inv * w[tid + 256] + bb[tid + 256];
  outf[ob + tid] = y0; outf[ob + tid + 256] = y1;
  if (outb) {
    outb[((size_t)m << 9) + tid]       = f2bf(y0);
    outb[((size_t)m << 9) + tid + 256] = f2bf(y1);
  }
}

// ---------------------------------------------------------------------------
// Decode kernels (per step, B=8)
// ---------------------------------------------------------------------------
__global__ __launch_bounds__(256) void dec_qkv(
    const float* __restrict__ xt, const float* __restrict__ qw,
    const float* __restrict__ qb, float* __restrict__ qt,
    float* __restrict__ kcv, float* __restrict__ vcv, int step)
{
  __shared__ float xs[512];
  const int b = blockIdx.y;
  const int tid = threadIdx.x;
  const int n = blockIdx.x * 256 + tid;
  xs[tid]       = xt[b * 512 + tid];
  xs[tid + 256] = xt[b * 512 + 256 + tid];
  __syncthreads();
  const float4* w4 = (const float4*)(qw + (size_t)n * 512);
  float acc = qb[n];
#pragma unroll 8
  for (int i = 0; i < 128; ++i) {
    float4 wv = w4[i];
    float4 xv = *(const float4*)&xs[i * 4];
    acc += xv.x * wv.x + xv.y * wv.y + xv.z * wv.z + xv.w * wv.w;
  }
  if (n < 512) {
    qt[b * 512 + n] = acc;
  } else {
    float* dst = (n < 1024) ? kcv : vcv;
    dst[((size_t)(b * CAP_ + S_ + step) << 9) + (n & 511)] = acc;
  }
}

__global__ __launch_bounds__(256) void dec_attn(
    const float* __restrict__ qt, const float* __restrict__ kcv,
    const float* __restrict__ vcv, float* __restrict__ at, int kv_len)
{
  __shared__ float qs[64];
  __shared__ float sc[CAP_];
  __shared__ float red[256];
  const int b = blockIdx.x >> 3, h = blockIdx.x & 7;
  const int tid = threadIdx.x;
  if (tid < 64) qs[tid] = qt[b * 512 + h * 64 + tid] * 0.125f;
  __syncthreads();

  for (int pos = tid; pos < kv_len; pos += 256) {
    const float4* k4 = (const float4*)(kcv + ((size_t)(b * CAP_ + pos) << 9) + h * 64);
    const float4* q4 = (const float4*)qs;
    float a = 0.f;
#pragma unroll
    for (int i = 0; i < 16; ++i) {
      float4 kv = k4[i]; float4 qv = q4[i];
      a += qv.x * kv.x + qv.y * kv.y + qv.z * kv.z + qv.w * kv.w;
    }
    sc[pos] = a;
  }
  __syncthreads();

  float mx = -1e30f;
  for (int pos = tid; pos < kv_len; pos += 256) mx = fmaxf(mx, sc[pos]);
  red[tid] = mx; __syncthreads();
  for (int st = 128; st > 0; st >>= 1) {
    if (tid < st) red[tid] = fmaxf(red[tid], red[tid + st]);
    __syncthreads();
  }
  float M = red[0]; __syncthreads();

  float sm = 0.f;
  for (int pos = tid; pos < kv_len; pos += 256) {
    float e = __expf(sc[pos] - M);
    sc[pos] = e; sm += e;
  }
  red[tid] = sm; __syncthreads();
  for (int st = 128; st > 0; st >>= 1) {
    if (tid < st) red[tid] += red[tid + st];
    __syncthreads();
  }
  float inv = 1.f / red[0]; __syncthreads();

  const int d = tid & 63, ch = tid >> 6;
  float o = 0.f;
#pragma unroll 4
  for (int t2 = ch; t2 < kv_len; t2 += 4)
    o += sc[t2] * vcv[((size_t)(b * CAP_ + t2) << 9) + h * 64 + d];
  red[tid] = o; __syncthreads();
  if (ch == 0)
    at[b * 512 + h * 64 + d] = (red[d] + red[64 + d] + red[128 + d] + red[192 + d]) * inv;
}

__global__ __launch_bounds__(512) void dec_proj_ln(
    const float* __restrict__ at, const float* __restrict__ xt,
    const float* __restrict__ ow, const float* __restrict__ obias,
    const float* __restrict__ lw, const float* __restrict__ lb,
    float* __restrict__ hd)
{
  __shared__ float as[512];
  __shared__ float s1[512], s2[512];
  const int b = blockIdx.x, e = threadIdx.x;
  as[e] = at[b * 512 + e];
  __syncthreads();
  const float4* w4 = (const float4*)(ow + (size_t)e * 512);
  float acc = obias[e];
#pragma unroll 8
  for (int i = 0; i < 128; ++i) {
    float4 wv = w4[i];
    float4 av = *(const float4*)&as[i * 4];
    acc += av.x * wv.x + av.y * wv.y + av.z * wv.z + av.w * wv.w;
  }
  float val = xt[b * 512 + e] + acc;
  s1[e] = val; s2[e] = val * val;
  __syncthreads();
  for (int st = 256; st > 0; st >>= 1) {
    if (e < st) { s1[e] += s1[e + st]; s2[e] += s2[e + st]; }
    __syncthreads();
  }
  float mu  = s1[0] * (1.f / 512.f);
  float var = s2[0] * (1.f / 512.f) - mu * mu;
  float inv = rsqrtf(var + EPS_);
  hd[b * 512 + e] = (val - mu) * inv * lw[e] + lb[e];
}

__global__ __launch_bounds__(256) void dec_mlp1(
    const float* __restrict__ hd, const float* __restrict__ w1,
    const float* __restrict__ b1, float* __restrict__ hid)
{
  __shared__ float xs[512];
  const int b = blockIdx.y;
  const int tid = threadIdx.x;
  const int f = blockIdx.x * 256 + tid;
  xs[tid]       = hd[b * 512 + tid];
  xs[tid + 256] = hd[b * 512 + 256 + tid];
  __syncthreads();
  const float4* w4 = (const float4*)(w1 + (size_t)f * 512);
  float acc = b1[f];
#pragma unroll 8
  for (int i = 0; i < 128; ++i) {
    float4 wv = w4[i];
    float4 xv = *(const float4*)&xs[i * 4];
    acc += xv.x * wv.x + xv.y * wv.y + xv.z * wv.z + xv.w * wv.w;
  }
  hid[b * 2048 + f] = fmaxf(acc, 0.f);
}

// MLP2 with 4-way K-split, 32 rows/block: w2 read exactly once per step.
__global__ __launch_bounds__(128) void dec_mlp2_part(
    const float* __restrict__ hid, const float* __restrict__ hd,
    const float* __restrict__ w2, const float* __restrict__ b2,
    float* __restrict__ m2out)
{
  __shared__ float red[32][4];
  const int nc = blockIdx.x, b = blockIdx.y;
  const int tid = threadIdx.x;
  const int nl = tid >> 2, ks = tid & 3;
  const int n = nc * 32 + nl;
  const float4* w4 = (const float4*)(w2 + (size_t)n * 2048 + ks * 512);
  const float4* h4 = (const float4*)(hid + (size_t)b * 2048 + ks * 512);
  float acc = 0.f;
#pragma unroll 8
  for (int i = 0; i < 128; ++i) {
    float4 wv = w4[i]; float4 hv = h4[i];
    acc += hv.x * wv.x + hv.y * wv.y + hv.z * wv.z + hv.w * wv.w;
  }
  red[nl][ks] = acc;
  __syncthreads();
  if (ks == 0) {
    float v = red[nl][0] + red[nl][1] + red[nl][2] + red[nl][3]
            + b2[n] + hd[b * 512 + n];
    m2out[b * 512 + n] = v;
  }
}

// ---------------------------------------------------------------------------
extern "C" void kernel_launch(void* const* d_in, const int* in_sizes, int n_in,
                              void* d_out, int out_size, void* d_ws, size_t ws_size,
                              hipStream_t stream)
{
  const float* x     = (const float*)d_in[0];
  const float* dx    = (const float*)d_in[1];
  const float* qkv_w = (const float*)d_in[3];
  const float* qkv_b = (const float*)d_in[4];
  const float* out_w = (const float*)d_in[5];
  const float* out_b = (const float*)d_in[6];
  const float* w1    = (const float*)d_in[7];
  const float* b1    = (const float*)d_in[8];
  const float* w2    = (const float*)d_in[9];
  const float* b2    = (const float*)d_in[10];
  const float* ln1w  = (const float*)d_in[11];
  const float* ln1b  = (const float*)d_in[12];
  const float* ln2w  = (const float*)d_in[13];
  const float* ln2b  = (const float*)d_in[14];
  float* out = (float*)d_out;

  float* ws = (float*)d_ws;
  size_t o = 0;
  unsigned short* x_bf    = (unsigned short*)(ws + o); o += (size_t)8192 * 256;  // also h1_bf
  unsigned short* qkvw_bf = (unsigned short*)(ws + o); o += 1536 * 256;
  unsigned short* outw_bf = (unsigned short*)(ws + o); o += 512 * 256;
  unsigned short* w1_bf   = (unsigned short*)(ws + o); o += 2048 * 256;
  unsigned short* w2_bf   = (unsigned short*)(ws + o); o += (size_t)512 * 1024;
  float* q_buf  = ws + o; o += (size_t)8192 * 512;          // also h2
  float* kc     = ws + o; o += (size_t)B_ * CAP_ * 512;
  float* vc     = ws + o; o += (size_t)B_ * CAP_ * 512;
  unsigned short* attn_bf = (unsigned short*)(ws + o); o += (size_t)8192 * 256;
  float* h      = ws + o; o += (size_t)8192 * 512;          // GEMM2 out, LN1 in-place
  unsigned short* hid_bf  = (unsigned short*)(ws + o); o += (size_t)8192 * 1024;
  float* q_t    = ws + o; o += 8 * 512;
  float* attn_t = ws + o; o += 8 * 512;
  float* h_t    = ws + o; o += 8 * 512;
  float* hid_t  = ws + o; o += 8 * 2048;
  float* m2out  = ws + o; o += 8 * 512;
  unsigned short* h1_bf = x_bf;   // reuse (x_bf dead after GEMM1)
  float* h2 = q_buf;              // reuse (q_buf dead after attention)

  // ---- weight / input conversions ----
  cvt_bf16<<<dim3(4096), 256, 0, stream>>>(x,     x_bf,    1048576);
  cvt_bf16<<<dim3(768),  256, 0, stream>>>(qkv_w, qkvw_bf, 196608);
  cvt_bf16<<<dim3(256),  256, 0, stream>>>(out_w, outw_bf, 65536);
  cvt_bf16<<<dim3(1024), 256, 0, stream>>>(w1,    w1_bf,   262144);
  cvt_bf16<<<dim3(1024), 256, 0, stream>>>(w2,    w2_bf,   262144);

  // ---- prefill ----
  mfma_gemm<<<dim3(64, 12), 256, 0, stream>>>(x_bf, qkvw_bf, qkv_b, nullptr,
      q_buf, kc, vc, nullptr, 8192, 1536, 512, 1, 0);
  attn_tile<<<dim3(16, 64), 256, 0, stream>>>(q_buf, kc, vc, attn_bf);
  mfma_gemm<<<dim3(64, 4), 256, 0, stream>>>(attn_bf, outw_bf, out_b, x,
      h, nullptr, nullptr, nullptr, 8192, 512, 512, 0, 0);
  ln_rows<<<dim3(8192), 256, 0, stream>>>(h, h, h1_bf, ln1w, ln1b, 0, 0);
  mfma_gemm<<<dim3(64, 16), 256, 0, stream>>>(h1_bf, w1_bf, b1, nullptr,
      nullptr, nullptr, nullptr, hid_bf, 8192, 2048, 512, 2, 1);
  mfma_gemm<<<dim3(64, 4), 256, 0, stream>>>(hid_bf, w2_bf, b2, h,
      h2, nullptr, nullptr, nullptr, 8192, 512, 2048, 0, 0);
  ln_rows<<<dim3(8192), 256, 0, stream>>>(h2, out, nullptr, ln2w, ln2b, 1, 0);

  // ---- decode: 64 sequential steps ----
  for (int t = 0; t < STEPS_; ++t) {
    const float* xt = dx + (size_t)t * B_ * 512;
    dec_qkv<<<dim3(6, 8), 256, 0, stream>>>(xt, qkv_w, qkv_b, q_t, kc, vc, t);
    dec_attn<<<dim3(64), 256, 0, stream>>>(q_t, kc, vc, attn_t, S_ + t + 1);
    dec_proj_ln<<<dim3(8), 512, 0, stream>>>(attn_t, xt, out_w, out_b, ln1w, ln1b, h_t);
    dec_mlp1<<<dim3(8, 8), 256, 0, stream>>>(h_t, w1, b1, hid_t);
    dec_mlp2_part<<<dim3(16, 8), 128, 0, stream>>>(hid_t, h_t, w2, b2, m2out);
    ln_rows<<<dim3(8), 256, 0, stream>>>(m2out, out, nullptr, ln2w, ln2b, 2, t);
  }
}

// Round 4
// 568.932 us; speedup vs baseline: 34.9726x; 14.6673x over previous
//
#include <hip/hip_runtime.h>
#include <cstdint>

#define CAP_ 1088
#define EPS_ 1e-5f

using bf8   = __attribute__((ext_vector_type(8))) short;
using f32x4 = __attribute__((ext_vector_type(4))) float;

__device__ __forceinline__ unsigned short f2bf(float f) {
  unsigned u = __float_as_uint(f);
  u += 0x7fffu + ((u >> 16) & 1);
  return (unsigned short)(u >> 16);
}

typedef const __attribute__((address_space(1))) void* gp1;
typedef __attribute__((address_space(3))) void* lp3;
__device__ __forceinline__ void async16(const void* g, void* l) {
  __builtin_amdgcn_global_load_lds((gp1)g, (lp3)l, 16, 0, 0);
}

// ---------------------------------------------------------------------------
// fp32 -> bf16 conversion (4 elems/thread)
// ---------------------------------------------------------------------------
__global__ __launch_bounds__(256) void cvt_bf16(const float* __restrict__ in,
                                                unsigned short* __restrict__ out,
                                                int n4) {
  int i = blockIdx.x * 256 + threadIdx.x;
  if (i >= n4) return;
  float4 v = ((const float4*)in)[i];
  ushort4 o;
  o.x = f2bf(v.x); o.y = f2bf(v.y); o.z = f2bf(v.z); o.w = f2bf(v.w);
  ((ushort4*)out)[i] = o;
}

// ---------------------------------------------------------------------------
// bf16 MFMA GEMM NT: C[M,N] = A[M,K] * B[N,K]^T + bias (+res, relu)
// 128x128 tile, BK=64, 4 waves (2x2 of 64x64), 16x16x32 MFMA.
// mode 0: fp32 C (+res, res2 for rows>=8192); mode 1: QKV routing
//   (q -> Cf row*512+col; k/v -> kc/vc; rows<8192 prefill (b,s),
//    rows>=8192 decode (b=r2&7, pos=1024+(r2>>3))); mode 2: bf16 C.
// ---------------------------------------------------------------------------
__global__ __launch_bounds__(256) void mfma_gemm(
    const unsigned short* __restrict__ A, const unsigned short* __restrict__ Bw,
    const float* __restrict__ bias, const float* __restrict__ res,
    const float* __restrict__ res2,
    float* __restrict__ Cf, float* __restrict__ kcv, float* __restrict__ vcv,
    unsigned short* __restrict__ Cb,
    int M, int N, int K, int mode, int relu)
{
  __shared__ unsigned short Als[128 * 64];
  __shared__ unsigned short Bls[128 * 64];
  const int tid  = threadIdx.x;
  const int lane = tid & 63, w = tid >> 6;
  const int bm = blockIdx.x * 128, bn = blockIdx.y * 128;
  const int wm = (w >> 1) * 64, wn = (w & 1) * 64;

  f32x4 acc[4][4] = {};

  const int so = tid * 16;
  for (int k0 = 0; k0 < K; k0 += 64) {
#pragma unroll
    for (int it = 0; it < 4; ++it) {
      int o   = it * 4096 + so;
      int row = o >> 7;             // 128 B per LDS row (64 bf16)
      int ch  = (o >> 4) & 7;
      int sch = ch ^ (row & 7);     // inverse-swizzled global source
      async16(A  + (size_t)(bm + row) * K + k0 + sch * 8, (char*)Als + o);
      async16(Bw + (size_t)(bn + row) * K + k0 + sch * 8, (char*)Bls + o);
    }
    __syncthreads();
#pragma unroll
    for (int ks = 0; ks < 2; ++ks) {
      bf8 af[4], bfr[4];
#pragma unroll
      for (int m = 0; m < 4; ++m) {
        int row = wm + m * 16 + (lane & 15);
        int ch  = ks * 4 + (lane >> 4);
        af[m] = *(const bf8*)((const char*)Als + row * 128 + ((ch ^ (row & 7)) * 16));
      }
#pragma unroll
      for (int n = 0; n < 4; ++n) {
        int row = wn + n * 16 + (lane & 15);
        int ch  = ks * 4 + (lane >> 4);
        bfr[n] = *(const bf8*)((const char*)Bls + row * 128 + ((ch ^ (row & 7)) * 16));
      }
#pragma unroll
      for (int m = 0; m < 4; ++m)
#pragma unroll
        for (int n = 0; n < 4; ++n)
          acc[m][n] = __builtin_amdgcn_mfma_f32_16x16x32_bf16(af[m], bfr[n], acc[m][n], 0, 0, 0);
    }
    __syncthreads();
  }

#pragma unroll
  for (int m = 0; m < 4; ++m) {
#pragma unroll
    for (int n = 0; n < 4; ++n) {
      int col = bn + wn + n * 16 + (lane & 15);
      float bcol = bias[col];
#pragma unroll
      for (int r = 0; r < 4; ++r) {
        int row = bm + wm + m * 16 + (lane >> 4) * 4 + r;
        float v = acc[m][n][r] + bcol;
        if (relu) v = fmaxf(v, 0.f);
        if (res) {
          if (res2 && row >= 8192) v += res2[((size_t)(row - 8192) << 9) + col];
          else                     v += res[(size_t)row * N + col];
        }
        if (mode == 0) {
          Cf[(size_t)row * N + col] = v;
        } else if (mode == 1) {
          if (col < 512) {
            Cf[((size_t)row << 9) + col] = v;
          } else {
            float* dst = (col < 1024) ? kcv : vcv;
            int bb, pos;
            if (row < 8192) { bb = row >> 10; pos = row & 1023; }
            else { int r2 = row - 8192; bb = r2 & 7; pos = 1024 + (r2 >> 3); }
            dst[(((size_t)(bb * CAP_ + pos)) << 9) + (col & 511)] = v;
          }
        } else {
          Cb[(size_t)row * N + col] = f2bf(v);
        }
      }
    }
  }
}

// ---------------------------------------------------------------------------
// Unified attention: fp32 vector math, 64-row Q tiles, online softmax.
// grid (17, 64): blockIdx.x = st (0..15 prefill s-tile; 16 = decode, where the
// 64 Q rows are the 64 decode steps), blockIdx.y = (b,h).
// Prefill row g = b*1024 + st*64 + r; decode row g = 8192 + r*8 + b.
// KV tiles t0 = 0..lastT0 (prefill lastT0 = st*64; decode = 1024); causal
// mask (col j > row r) applied on the final tile in both cases.
// ---------------------------------------------------------------------------
__global__ __launch_bounds__(256) void attn_all(
    const float* __restrict__ q_buf, const float* __restrict__ kc,
    const float* __restrict__ vc, unsigned short* __restrict__ ob)
{
  __shared__ float Qls[64][64];
  __shared__ float KV[64][64];
  __shared__ float St[64][68];
  const int st = blockIdx.x, bh = blockIdx.y;
  const int b = bh >> 3, h = bh & 7;
  const bool dec = (st == 16);
  const int tid = threadIdx.x;
  const int tx = tid & 15, ty = tid >> 4;
  const int lastT0 = dec ? 1024 : st * 64;
  const size_t bbase = (size_t)b * CAP_ * 512;

  { // stage Q (scaled by 1/8) transposed -> Qls[d][r]
    const int row = tid & 63, c0 = tid >> 6;
    const size_t g = dec ? (size_t)(8192 + row * 8 + b)
                         : (size_t)((b << 10) + st * 64 + row);
    const float* qr = q_buf + (g << 9) + h * 64;
#pragma unroll
    for (int i = 0; i < 4; ++i) {
      int dc = c0 + i * 4;
      float4 v = *(const float4*)(qr + dc * 4);
      Qls[dc * 4 + 0][row] = v.x * 0.125f;
      Qls[dc * 4 + 1][row] = v.y * 0.125f;
      Qls[dc * 4 + 2][row] = v.z * 0.125f;
      Qls[dc * 4 + 3][row] = v.w * 0.125f;
    }
  }

  float m_[4], l_[4], o_[4][4];
#pragma unroll
  for (int i = 0; i < 4; ++i) {
    m_[i] = -1e30f; l_[i] = 0.f;
#pragma unroll
    for (int j = 0; j < 4; ++j) o_[i][j] = 0.f;
  }

  for (int t0 = 0; t0 <= lastT0; t0 += 64) {
    __syncthreads();               // prev PV done with KV & St (and Q staged)
    { // stage K transposed -> KV[d][r]
      const int row = tid & 63, c0 = tid >> 6;
      const float* kr = kc + bbase + (((size_t)(t0 + row)) << 9) + h * 64;
#pragma unroll
      for (int i = 0; i < 4; ++i) {
        int dc = c0 + i * 4;
        float4 v = *(const float4*)(kr + dc * 4);
        KV[dc * 4 + 0][row] = v.x; KV[dc * 4 + 1][row] = v.y;
        KV[dc * 4 + 2][row] = v.z; KV[dc * 4 + 3][row] = v.w;
      }
    }
    __syncthreads();

    float p[4][4];
#pragma unroll
    for (int i = 0; i < 4; ++i)
#pragma unroll
      for (int j = 0; j < 4; ++j) p[i][j] = 0.f;
#pragma unroll 4
    for (int d = 0; d < 64; ++d) {
      float4 qv = *(const float4*)&Qls[d][ty * 4];
      float4 kv = *(const float4*)&KV[d][tx * 4];
      float qa[4] = {qv.x, qv.y, qv.z, qv.w};
      float ka[4] = {kv.x, kv.y, kv.z, kv.w};
#pragma unroll
      for (int i = 0; i < 4; ++i)
#pragma unroll
        for (int j = 0; j < 4; ++j) p[i][j] = fmaf(qa[i], ka[j], p[i][j]);
    }
    if (t0 == lastT0) {            // causal mask on final tile
#pragma unroll
      for (int i = 0; i < 4; ++i) {
        int rg = ty * 4 + i;
#pragma unroll
        for (int j = 0; j < 4; ++j)
          if (tx * 4 + j > rg) p[i][j] = -1e30f;
      }
    }
#pragma unroll
    for (int i = 0; i < 4; ++i) {
      float rm = fmaxf(fmaxf(p[i][0], p[i][1]), fmaxf(p[i][2], p[i][3]));
#pragma unroll
      for (int off = 1; off < 16; off <<= 1) rm = fmaxf(rm, __shfl_xor(rm, off, 64));
      float mn = fmaxf(m_[i], rm);
      float f  = __expf(m_[i] - mn);
      float rs = 0.f;
#pragma unroll
      for (int j = 0; j < 4; ++j) { p[i][j] = __expf(p[i][j] - mn); rs += p[i][j]; }
#pragma unroll
      for (int off = 1; off < 16; off <<= 1) rs += __shfl_xor(rs, off, 64);
      l_[i] = l_[i] * f + rs;
      m_[i] = mn;
#pragma unroll
      for (int j = 0; j < 4; ++j) o_[i][j] *= f;
    }
#pragma unroll
    for (int j = 0; j < 4; ++j) {
      float4 col = make_float4(p[0][j], p[1][j], p[2][j], p[3][j]);
      *(float4*)&St[tx * 4 + j][ty * 4] = col;
    }
    __syncthreads();               // K reads done + St visible
    { // stage V natural -> KV[r][d]
      const int c = tid & 15, r4 = tid >> 4;
#pragma unroll
      for (int i = 0; i < 4; ++i) {
        int row = r4 + i * 16;
        float4 v = *(const float4*)(vc + bbase + (((size_t)(t0 + row)) << 9) + h * 64 + c * 4);
        *(float4*)&KV[row][c * 4] = v;
      }
    }
    __syncthreads();
#pragma unroll 4
    for (int k = 0; k < 64; ++k) {
      float4 pv = *(const float4*)&St[k][ty * 4];
      float4 vv = *(const float4*)&KV[k][tx * 4];
      float pa[4] = {pv.x, pv.y, pv.z, pv.w};
      float va[4] = {vv.x, vv.y, vv.z, vv.w};
#pragma unroll
      for (int i = 0; i < 4; ++i)
#pragma unroll
        for (int j = 0; j < 4; ++j) o_[i][j] = fmaf(pa[i], va[j], o_[i][j]);
    }
  }
#pragma unroll
  for (int i = 0; i < 4; ++i) {
    int r = ty * 4 + i;
    size_t g = dec ? (size_t)(8192 + r * 8 + b)
                   : (size_t)((b << 10) + st * 64 + r);
    float inv = 1.f / l_[i];
    ushort4 pk;
    pk.x = f2bf(o_[i][0] * inv); pk.y = f2bf(o_[i][1] * inv);
    pk.z = f2bf(o_[i][2] * inv); pk.w = f2bf(o_[i][3] * inv);
    *(ushort4*)(ob + (g << 9) + h * 64 + tx * 4) = pk;
  }
}

// ---------------------------------------------------------------------------
// Row LayerNorm over D=512.
// outmode 0: outf[m*512] (+opt bf16 copy at outb[m*512]).
// outmode 5: final routing to d_out: m<8192 -> (b=m>>10, s=m&1023);
//            m>=8192 -> r2=m-8192, (b=r2&7, s=1024+(r2>>3)).
// ---------------------------------------------------------------------------
__global__ __launch_bounds__(256) void ln_rows(
    const float* __restrict__ in, float* __restrict__ outf,
    unsigned short* __restrict__ outb,
    const float* __restrict__ w, const float* __restrict__ bb,
    int outmode)
{
  __shared__ float s1[256], s2[256];
  const int m = blockIdx.x, tid = threadIdx.x;
  const float* row = in + ((size_t)m << 9);
  float x0 = row[tid], x1 = row[tid + 256];
  s1[tid] = x0 + x1;
  s2[tid] = x0 * x0 + x1 * x1;
  __syncthreads();
  for (int st = 128; st > 0; st >>= 1) {
    if (tid < st) { s1[tid] += s1[tid + st]; s2[tid] += s2[tid + st]; }
    __syncthreads();
  }
  float mu  = s1[0] * (1.f / 512.f);
  float var = s2[0] * (1.f / 512.f) - mu * mu;
  float inv = rsqrtf(var + EPS_);
  size_t ob;
  if (outmode == 0) ob = (size_t)m << 9;
  else {
    int b, s;
    if (m < 8192) { b = m >> 10; s = m & 1023; }
    else { int r2 = m - 8192; b = r2 & 7; s = 1024 + (r2 >> 3); }
    ob = ((size_t)(b * CAP_ + s)) << 9;
  }
  float y0 = (x0 - mu) * inv * w[tid] + bb[tid];
  float y1 = (x1 - mu) * inv * w[tid + 256] + bb[tid + 256];
  outf[ob + tid] = y0; outf[ob + tid + 256] = y1;
  if (outb) {
    outb[((size_t)m << 9) + tid]       = f2bf(y0);
    outb[((size_t)m << 9) + tid + 256] = f2bf(y1);
  }
}

// ---------------------------------------------------------------------------
extern "C" void kernel_launch(void* const* d_in, const int* in_sizes, int n_in,
                              void* d_out, int out_size, void* d_ws, size_t ws_size,
                              hipStream_t stream)
{
  const float* x     = (const float*)d_in[0];
  const float* dx    = (const float*)d_in[1];   // [64,8,1,512] rows t*8+b
  const float* qkv_w = (const float*)d_in[3];
  const float* qkv_b = (const float*)d_in[4];
  const float* out_w = (const float*)d_in[5];
  const float* out_b = (const float*)d_in[6];
  const float* w1    = (const float*)d_in[7];
  const float* b1    = (const float*)d_in[8];
  const float* w2    = (const float*)d_in[9];
  const float* b2    = (const float*)d_in[10];
  const float* ln1w  = (const float*)d_in[11];
  const float* ln1b  = (const float*)d_in[12];
  const float* ln2w  = (const float*)d_in[13];
  const float* ln2b  = (const float*)d_in[14];
  float* out = (float*)d_out;

  // M = 8704 rows everywhere: 8192 prefill tokens + 512 decode tokens (t*8+b)
  float* ws = (float*)d_ws;
  size_t o = 0;
  unsigned short* x_bf    = (unsigned short*)(ws + o); o += (size_t)8704 * 256;
  unsigned short* qkvw_bf = (unsigned short*)(ws + o); o += 1536 * 256;
  unsigned short* outw_bf = (unsigned short*)(ws + o); o += 512 * 256;
  unsigned short* w1_bf   = (unsigned short*)(ws + o); o += 2048 * 256;
  unsigned short* w2_bf   = (unsigned short*)(ws + o); o += (size_t)512 * 1024;
  float* q_buf  = ws + o; o += (size_t)8704 * 512;          // also MLP2 out
  float* kc     = ws + o; o += (size_t)8 * CAP_ * 512;
  float* vc     = ws + o; o += (size_t)8 * CAP_ * 512;
  unsigned short* attn_bf = (unsigned short*)(ws + o); o += (size_t)8704 * 256;
  float* h      = ws + o; o += (size_t)8704 * 512;          // proj out, LN1 in-place
  unsigned short* h_bf    = (unsigned short*)(ws + o); o += (size_t)8704 * 256;
  unsigned short* hid_bf  = (unsigned short*)(ws + o); o += (size_t)8704 * 1024;
  float* h2 = q_buf;   // reuse: q_buf dead after attn_all

  // ---- conversions ----
  cvt_bf16<<<dim3(4096), 256, 0, stream>>>(x,  x_bf,              1048576);
  cvt_bf16<<<dim3(256),  256, 0, stream>>>(dx, x_bf + (size_t)8192 * 512, 65536);
  cvt_bf16<<<dim3(768),  256, 0, stream>>>(qkv_w, qkvw_bf, 196608);
  cvt_bf16<<<dim3(256),  256, 0, stream>>>(out_w, outw_bf, 65536);
  cvt_bf16<<<dim3(1024), 256, 0, stream>>>(w1,    w1_bf,   262144);
  cvt_bf16<<<dim3(1024), 256, 0, stream>>>(w2,    w2_bf,   262144);

  // ---- QKV for prefill + all 64 decode steps in one GEMM ----
  mfma_gemm<<<dim3(68, 12), 256, 0, stream>>>(x_bf, qkvw_bf, qkv_b, nullptr, nullptr,
      q_buf, kc, vc, nullptr, 8704, 1536, 512, 1, 0);
  // ---- prefill attention (st 0..15) + decode attention (st 16) ----
  attn_all<<<dim3(17, 64), 256, 0, stream>>>(q_buf, kc, vc, attn_bf);
  // ---- out-proj + residual (x for prefill rows, dx for decode rows) ----
  mfma_gemm<<<dim3(68, 4), 256, 0, stream>>>(attn_bf, outw_bf, out_b, x, dx,
      h, nullptr, nullptr, nullptr, 8704, 512, 512, 0, 0);
  ln_rows<<<dim3(8704), 256, 0, stream>>>(h, h, h_bf, ln1w, ln1b, 0);
  // ---- MLP ----
  mfma_gemm<<<dim3(68, 16), 256, 0, stream>>>(h_bf, w1_bf, b1, nullptr, nullptr,
      nullptr, nullptr, nullptr, hid_bf, 8704, 2048, 512, 2, 1);
  mfma_gemm<<<dim3(68, 4), 256, 0, stream>>>(hid_bf, w2_bf, b2, h, nullptr,
      h2, nullptr, nullptr, nullptr, 8704, 512, 2048, 0, 0);
  ln_rows<<<dim3(8704), 256, 0, stream>>>(h2, out, nullptr, ln2w, ln2b, 5);
}

// Round 5
// 350.111 us; speedup vs baseline: 56.8307x; 1.6250x over previous
//
#include <hip/hip_runtime.h>
#include <cstdint>

#define CAP_ 1088
#define EPS_ 1e-5f

using bf8   = __attribute__((ext_vector_type(8))) short;
using f32x4 = __attribute__((ext_vector_type(4))) float;

__device__ __forceinline__ unsigned short f2bf(float f) {
  unsigned u = __float_as_uint(f);
  u += 0x7fffu + ((u >> 16) & 1);
  return (unsigned short)(u >> 16);
}

typedef const __attribute__((address_space(1))) void* gp1;
typedef __attribute__((address_space(3))) void* lp3;
__device__ __forceinline__ void async16(const void* g, void* l) {
  __builtin_amdgcn_global_load_lds((gp1)g, (lp3)l, 16, 0, 0);
}

// ---------------------------------------------------------------------------
// fp32 -> bf16 conversion (4 elems/thread)
// ---------------------------------------------------------------------------
__global__ __launch_bounds__(256) void cvt_bf16(const float* __restrict__ in,
                                                unsigned short* __restrict__ out,
                                                int n4) {
  int i = blockIdx.x * 256 + threadIdx.x;
  if (i >= n4) return;
  float4 v = ((const float4*)in)[i];
  ushort4 o;
  o.x = f2bf(v.x); o.y = f2bf(v.y); o.z = f2bf(v.z); o.w = f2bf(v.w);
  ((ushort4*)out)[i] = o;
}

// ---------------------------------------------------------------------------
// bf16 MFMA GEMM NT: C[M,N] = A[M,K] * B[N,K]^T + bias (+res, relu)
// 128x128 tile, BK=64, 4 waves (2x2 of 64x64), 16x16x32 MFMA.
// mode 0: fp32 C (+res; res2 for rows>=8192)
// mode 1: QKV routing, all bf16: col<512 -> Cb q (scaled 1/8, [row][512]);
//         col<1024 -> kb [b][pos][512]; else -> vt [b][h][d][CAP] (V^T).
//         rows<8192: prefill (b=row>>10, pos=row&1023); rows>=8192: decode
//         (r2=row-8192, b=r2&7, pos=1024+(r2>>3)).
// mode 2: bf16 C.
// ---------------------------------------------------------------------------
__global__ __launch_bounds__(256) void mfma_gemm(
    const unsigned short* __restrict__ A, const unsigned short* __restrict__ Bw,
    const float* __restrict__ bias, const float* __restrict__ res,
    const float* __restrict__ res2,
    float* __restrict__ Cf, unsigned short* __restrict__ Cb,
    unsigned short* __restrict__ kb, unsigned short* __restrict__ vt,
    int M, int N, int K, int mode, int relu)
{
  __shared__ unsigned short Als[128 * 64];
  __shared__ unsigned short Bls[128 * 64];
  const int tid  = threadIdx.x;
  const int lane = tid & 63, w = tid >> 6;
  const int bm = blockIdx.x * 128, bn = blockIdx.y * 128;
  const int wm = (w >> 1) * 64, wn = (w & 1) * 64;

  f32x4 acc[4][4] = {};

  const int so = tid * 16;
  for (int k0 = 0; k0 < K; k0 += 64) {
#pragma unroll
    for (int it = 0; it < 4; ++it) {
      int o   = it * 4096 + so;
      int row = o >> 7;             // 128 B per LDS row (64 bf16)
      int ch  = (o >> 4) & 7;
      int sch = ch ^ (row & 7);     // inverse-swizzled global source
      async16(A  + (size_t)(bm + row) * K + k0 + sch * 8, (char*)Als + o);
      async16(Bw + (size_t)(bn + row) * K + k0 + sch * 8, (char*)Bls + o);
    }
    __syncthreads();
#pragma unroll
    for (int ks = 0; ks < 2; ++ks) {
      bf8 af[4], bfr[4];
#pragma unroll
      for (int m = 0; m < 4; ++m) {
        int row = wm + m * 16 + (lane & 15);
        int ch  = ks * 4 + (lane >> 4);
        af[m] = *(const bf8*)((const char*)Als + row * 128 + ((ch ^ (row & 7)) * 16));
      }
#pragma unroll
      for (int n = 0; n < 4; ++n) {
        int row = wn + n * 16 + (lane & 15);
        int ch  = ks * 4 + (lane >> 4);
        bfr[n] = *(const bf8*)((const char*)Bls + row * 128 + ((ch ^ (row & 7)) * 16));
      }
#pragma unroll
      for (int m = 0; m < 4; ++m)
#pragma unroll
        for (int n = 0; n < 4; ++n)
          acc[m][n] = __builtin_amdgcn_mfma_f32_16x16x32_bf16(af[m], bfr[n], acc[m][n], 0, 0, 0);
    }
    __syncthreads();
  }

#pragma unroll
  for (int m = 0; m < 4; ++m) {
#pragma unroll
    for (int n = 0; n < 4; ++n) {
      int col  = bn + wn + n * 16 + (lane & 15);
      int row0 = bm + wm + m * 16 + ((lane >> 4) << 2);
      float bcol = bias[col];
      if (mode == 1) {
        if (col < 512) {
#pragma unroll
          for (int r = 0; r < 4; ++r)
            Cb[((size_t)(row0 + r) << 9) + col] = f2bf((acc[m][n][r] + bcol) * 0.125f);
        } else if (col < 1024) {
#pragma unroll
          for (int r = 0; r < 4; ++r) {
            int row = row0 + r; int bb, pos;
            if (row < 8192) { bb = row >> 10; pos = row & 1023; }
            else { int r2 = row - 8192; bb = r2 & 7; pos = 1024 + (r2 >> 3); }
            kb[(((size_t)(bb * CAP_ + pos)) << 9) + (col - 512)] = f2bf(acc[m][n][r] + bcol);
          }
        } else {
          int c = col - 1024; int hh = c >> 6, d = c & 63;
          if (row0 < 8192) {        // 4 consecutive pos within one b
            int bb = row0 >> 10, pos = row0 & 1023;
            ushort4 pk;
            pk.x = f2bf(acc[m][n][0] + bcol); pk.y = f2bf(acc[m][n][1] + bcol);
            pk.z = f2bf(acc[m][n][2] + bcol); pk.w = f2bf(acc[m][n][3] + bcol);
            *(ushort4*)(vt + ((size_t)((bb * 8 + hh) * 64 + d)) * CAP_ + pos) = pk;
          } else {
#pragma unroll
            for (int r = 0; r < 4; ++r) {
              int r2 = row0 + r - 8192; int bb = r2 & 7, pos = 1024 + (r2 >> 3);
              vt[((size_t)((bb * 8 + hh) * 64 + d)) * CAP_ + pos] = f2bf(acc[m][n][r] + bcol);
            }
          }
        }
      } else {
#pragma unroll
        for (int r = 0; r < 4; ++r) {
          int row = row0 + r;
          float v = acc[m][n][r] + bcol;
          if (relu) v = fmaxf(v, 0.f);
          if (res) {
            if (res2 && row >= 8192) v += res2[((size_t)(row - 8192) << 9) + col];
            else                     v += res[(size_t)row * N + col];
          }
          if (mode == 0) Cf[(size_t)row * N + col] = v;
          else           Cb[(size_t)row * N + col] = f2bf(v);
        }
      }
    }
  }
}

// ---------------------------------------------------------------------------
// MFMA attention. grid (17,64): x = q-tile (16 = decode tile), y = (b,h).
// 256 thr = 4 waves; wave w owns q rows [w*16, w*16+16) of the 64-row tile.
// Swapped QK: S^T = mfma(K, Q) so each lane owns one q-row (q = w*16+lane&15,
// 16 t-values). Softmax: 2 shfl_xor. PV as O^T = mfma(V^T, P): stats and
// output share lanes. K and V^T staged via async16 + XOR swizzle; P repacked
// via 4x ds_write_b64.
// ---------------------------------------------------------------------------
__global__ __launch_bounds__(256) void attn_mfma(
    const unsigned short* __restrict__ qb,   // [8704][512], pre-scaled 1/8
    const unsigned short* __restrict__ kcb,  // [8][1088][512]
    const unsigned short* __restrict__ vtb,  // [8][8][64][1088]
    unsigned short* __restrict__ ob)         // [8704][512]
{
  __shared__ unsigned short Kls[4096];   // [t][64d] swizzled, 128B rows
  __shared__ unsigned short Vls[4096];   // [d][64t] swizzled
  __shared__ unsigned short Pls[4096];   // [q][64t] swizzled
  const int st = blockIdx.x, bh = blockIdx.y;
  const int b = bh >> 3, h = bh & 7;
  const bool dec = (st == 16);
  const int tid = threadIdx.x, lane = tid & 63, w = tid >> 6;
  const int wq = w * 16;
  const int nT = dec ? 17 : st + 1;
  const int qi = wq + (lane & 15);            // q row within tile (0..63)
  const size_t g = dec ? (size_t)(8192 + qi * 8 + b)
                       : (size_t)((b << 10) + st * 64 + qi);

  const bf8 qf0 = *(const bf8*)(qb + (g << 9) + h * 64 +      ((lane >> 4) << 3));
  const bf8 qf1 = *(const bf8*)(qb + (g << 9) + h * 64 + 32 + ((lane >> 4) << 3));

  f32x4 oo[4] = {};
  float m_ = -1e30f, l_ = 0.f;

  const size_t kbase = (((size_t)b * CAP_) << 9) + h * 64;
  const size_t vbase = (size_t)((b * 8 + h) * 64) * CAP_;

  for (int t = 0; t < nT; ++t) {
    const int t0 = t * 64;
    __syncthreads();                          // prev PV reads done
#pragma unroll
    for (int it = 0; it < 2; ++it) {
      int o   = it * 4096 + tid * 16;         // byte offset in 8KB buffer
      int row = o >> 7;
      int sch = ((o >> 4) & 7) ^ (row & 7);
      async16(kcb + kbase + (((size_t)(t0 + row)) << 9) + sch * 8, (char*)Kls + o);
      async16(vtb + vbase + (size_t)row * CAP_ + t0 + sch * 8,     (char*)Vls + o);
    }
    __syncthreads();                          // staged (vmcnt drained)

    // ---- QK^T (swapped): D[t][q] ----
    f32x4 sfr[4] = {};
#pragma unroll
    for (int ks = 0; ks < 2; ++ks) {
      int cb = ks * 4 + (lane >> 4);
      bf8 qv = ks ? qf1 : qf0;
#pragma unroll
      for (int f = 0; f < 4; ++f) {
        int row = f * 16 + (lane & 15);
        bf8 kf = *(const bf8*)((const char*)Kls + row * 128 + ((cb ^ (row & 7)) << 4));
        sfr[f] = __builtin_amdgcn_mfma_f32_16x16x32_bf16(kf, qv, sfr[f], 0, 0, 0);
      }
    }
    if (t == nT - 1) {                        // causal mask (prefill & decode)
#pragma unroll
      for (int f = 0; f < 4; ++f)
#pragma unroll
        for (int r = 0; r < 4; ++r) {
          int tr = f * 16 + ((lane >> 4) << 2) + r;
          if (tr > qi) sfr[f][r] = -1e30f;
        }
    }

    // ---- online softmax: lane owns q=qi, 16 t-values ----
    float pmax = -1e30f;
#pragma unroll
    for (int f = 0; f < 4; ++f)
#pragma unroll
      for (int r = 0; r < 4; ++r) pmax = fmaxf(pmax, sfr[f][r]);
    pmax = fmaxf(pmax, __shfl_xor(pmax, 16, 64));
    pmax = fmaxf(pmax, __shfl_xor(pmax, 32, 64));
    float mn  = fmaxf(m_, pmax);
    float fsc = __expf(m_ - mn);
    float rs = 0.f;
#pragma unroll
    for (int f = 0; f < 4; ++f)
#pragma unroll
      for (int r = 0; r < 4; ++r) {
        float e = __expf(sfr[f][r] - mn);
        sfr[f][r] = e; rs += e;
      }
    rs += __shfl_xor(rs, 16, 64);
    rs += __shfl_xor(rs, 32, 64);
    l_ = l_ * fsc + rs; m_ = mn;
#pragma unroll
    for (int f = 0; f < 4; ++f) oo[f] *= fsc;

    // ---- P -> Pls[q][t] (bf16, packed b64, swizzled) ----
#pragma unroll
    for (int f = 0; f < 4; ++f) {
      ushort4 pk;
      pk.x = f2bf(sfr[f][0]); pk.y = f2bf(sfr[f][1]);
      pk.z = f2bf(sfr[f][2]); pk.w = f2bf(sfr[f][3]);
      int tb   = f * 32 + ((lane >> 4) << 3);         // byte offset of t
      int addr = qi * 128 + ((((tb >> 4)) ^ (qi & 7)) << 4) + (tb & 15);
      *(ushort4*)((char*)Pls + addr) = pk;
    }
    __syncthreads();                          // Pls visible; Kls reads done

    // ---- PV: O^T[d][q] += mfma(V^T rows, P rows) ----
#pragma unroll
    for (int ks = 0; ks < 2; ++ks) {
      int cb = ks * 4 + (lane >> 4);
      bf8 pf = *(const bf8*)((const char*)Pls + qi * 128 + ((cb ^ (qi & 7)) << 4));
#pragma unroll
      for (int f = 0; f < 4; ++f) {
        int row = f * 16 + (lane & 15);
        bf8 vf = *(const bf8*)((const char*)Vls + row * 128 + ((cb ^ (row & 7)) << 4));
        oo[f] = __builtin_amdgcn_mfma_f32_16x16x32_bf16(vf, pf, oo[f], 0, 0, 0);
      }
    }
  }

  const float inv = 1.f / l_;
#pragma unroll
  for (int f = 0; f < 4; ++f) {
    ushort4 pk;
    pk.x = f2bf(oo[f][0] * inv); pk.y = f2bf(oo[f][1] * inv);
    pk.z = f2bf(oo[f][2] * inv); pk.w = f2bf(oo[f][3] * inv);
    int d0 = f * 16 + ((lane >> 4) << 2);
    *(ushort4*)(ob + (g << 9) + h * 64 + d0) = pk;
  }
}

// ---------------------------------------------------------------------------
// Row LayerNorm over D=512.
// outmode 0: outf[m*512] (+opt bf16 copy at outb[m*512]).
// outmode 5: final routing to d_out: m<8192 -> (b=m>>10, s=m&1023);
//            m>=8192 -> r2=m-8192, (b=r2&7, s=1024+(r2>>3)).
// ---------------------------------------------------------------------------
__global__ __launch_bounds__(256) void ln_rows(
    const float* __restrict__ in, float* __restrict__ outf,
    unsigned short* __restrict__ outb,
    const float* __restrict__ w, const float* __restrict__ bb,
    int outmode)
{
  __shared__ float s1[256], s2[256];
  const int m = blockIdx.x, tid = threadIdx.x;
  const float* row = in + ((size_t)m << 9);
  float x0 = row[tid], x1 = row[tid + 256];
  s1[tid] = x0 + x1;
  s2[tid] = x0 * x0 + x1 * x1;
  __syncthreads();
  for (int st = 128; st > 0; st >>= 1) {
    if (tid < st) { s1[tid] += s1[tid + st]; s2[tid] += s2[tid + st]; }
    __syncthreads();
  }
  float mu  = s1[0] * (1.f / 512.f);
  float var = s2[0] * (1.f / 512.f) - mu * mu;
  float inv = rsqrtf(var + EPS_);
  size_t ob;
  if (outmode == 0) ob = (size_t)m << 9;
  else {
    int b, s;
    if (m < 8192) { b = m >> 10; s = m & 1023; }
    else { int r2 = m - 8192; b = r2 & 7; s = 1024 + (r2 >> 3); }
    ob = ((size_t)(b * CAP_ + s)) << 9;
  }
  float y0 = (x0 - mu) * inv * w[tid] + bb[tid];
  float y1 = (x1 - mu) * inv * w[tid + 256] + bb[tid + 256];
  outf[ob + tid] = y0; outf[ob + tid + 256] = y1;
  if (outb) {
    outb[((size_t)m << 9) + tid]       = f2bf(y0);
    outb[((size_t)m << 9) + tid + 256] = f2bf(y1);
  }
}

// ---------------------------------------------------------------------------
extern "C" void kernel_launch(void* const* d_in, const int* in_sizes, int n_in,
                              void* d_out, int out_size, void* d_ws, size_t ws_size,
                              hipStream_t stream)
{
  const float* x     = (const float*)d_in[0];
  const float* dx    = (const float*)d_in[1];   // [64,8,1,512] rows t*8+b
  const float* qkv_w = (const float*)d_in[3];
  const float* qkv_b = (const float*)d_in[4];
  const float* out_w = (const float*)d_in[5];
  const float* out_b = (const float*)d_in[6];
  const float* w1    = (const float*)d_in[7];
  const float* b1    = (const float*)d_in[8];
  const float* w2    = (const float*)d_in[9];
  const float* b2    = (const float*)d_in[10];
  const float* ln1w  = (const float*)d_in[11];
  const float* ln1b  = (const float*)d_in[12];
  const float* ln2w  = (const float*)d_in[13];
  const float* ln2b  = (const float*)d_in[14];
  float* out = (float*)d_out;

  // M = 8704 rows: 8192 prefill tokens + 512 decode tokens (row 8192 + t*8+b)
  float* ws = (float*)d_ws;
  size_t o = 0;
  unsigned short* x_bf    = (unsigned short*)(ws + o); o += (size_t)8704 * 256;
  unsigned short* qkvw_bf = (unsigned short*)(ws + o); o += 1536 * 256;
  unsigned short* outw_bf = (unsigned short*)(ws + o); o += 512 * 256;
  unsigned short* w1_bf   = (unsigned short*)(ws + o); o += 2048 * 256;
  unsigned short* w2_bf   = (unsigned short*)(ws + o); o += (size_t)512 * 1024;
  unsigned short* qb_bf   = (unsigned short*)(ws + o); o += (size_t)8704 * 256;
  unsigned short* kcb     = (unsigned short*)(ws + o); o += (size_t)8 * CAP_ * 256;
  unsigned short* vtb     = (unsigned short*)(ws + o); o += (size_t)8 * 512 * CAP_ / 2;
  unsigned short* attn_bf = (unsigned short*)(ws + o); o += (size_t)8704 * 256;
  float* h                = ws + o;                    o += (size_t)8704 * 512;
  unsigned short* h_bf    = (unsigned short*)(ws + o); o += (size_t)8704 * 256;
  unsigned short* hid_bf  = (unsigned short*)(ws + o); o += (size_t)8704 * 1024;
  float* h2               = ws + o;                    o += (size_t)8704 * 512;

  // ---- conversions ----
  cvt_bf16<<<dim3(4096), 256, 0, stream>>>(x,  x_bf,                      1048576);
  cvt_bf16<<<dim3(256),  256, 0, stream>>>(dx, x_bf + (size_t)8192 * 512, 65536);
  cvt_bf16<<<dim3(768),  256, 0, stream>>>(qkv_w, qkvw_bf, 196608);
  cvt_bf16<<<dim3(256),  256, 0, stream>>>(out_w, outw_bf, 65536);
  cvt_bf16<<<dim3(1024), 256, 0, stream>>>(w1,    w1_bf,   262144);
  cvt_bf16<<<dim3(1024), 256, 0, stream>>>(w2,    w2_bf,   262144);

  // ---- QKV (prefill + all decode steps), outputs bf16 q / K-cache / V^T ----
  mfma_gemm<<<dim3(68, 12), 256, 0, stream>>>(x_bf, qkvw_bf, qkv_b, nullptr, nullptr,
      nullptr, qb_bf, kcb, vtb, 8704, 1536, 512, 1, 0);
  // ---- attention: prefill tiles 0..15 + decode tile 16 ----
  attn_mfma<<<dim3(17, 64), 256, 0, stream>>>(qb_bf, kcb, vtb, attn_bf);
  // ---- out-proj + residual (x for prefill rows, dx for decode rows) ----
  mfma_gemm<<<dim3(68, 4), 256, 0, stream>>>(attn_bf, outw_bf, out_b, x, dx,
      h, nullptr, nullptr, nullptr, 8704, 512, 512, 0, 0);
  ln_rows<<<dim3(8704), 256, 0, stream>>>(h, h, h_bf, ln1w, ln1b, 0);
  // ---- MLP ----
  mfma_gemm<<<dim3(68, 16), 256, 0, stream>>>(h_bf, w1_bf, b1, nullptr, nullptr,
      nullptr, hid_bf, nullptr, nullptr, 8704, 2048, 512, 2, 1);
  mfma_gemm<<<dim3(68, 4), 256, 0, stream>>>(hid_bf, w2_bf, b2, h, nullptr,
      h2, nullptr, nullptr, nullptr, 8704, 512, 2048, 0, 0);
  ln_rows<<<dim3(8704), 256, 0, stream>>>(h2, out, nullptr, ln2w, ln2b, 5);
}

// Round 6
// 310.454 us; speedup vs baseline: 64.0902x; 1.1277x over previous
//
#include <hip/hip_runtime.h>
#include <cstdint>

#define CAP_ 1088
#define EPS_ 1e-5f

using bf8   = __attribute__((ext_vector_type(8))) short;
using f32x4 = __attribute__((ext_vector_type(4))) float;

__device__ __forceinline__ unsigned short f2bf(float f) {
  unsigned u = __float_as_uint(f);
  u += 0x7fffu + ((u >> 16) & 1);
  return (unsigned short)(u >> 16);
}
__device__ __forceinline__ float bf2f(unsigned short v) {
  return __uint_as_float((unsigned)v << 16);
}

typedef const __attribute__((address_space(1))) void* gp1;
typedef __attribute__((address_space(3))) void* lp3;
__device__ __forceinline__ void async16(const void* g, void* l) {
  __builtin_amdgcn_global_load_lds((gp1)g, (lp3)l, 16, 0, 0);
}

// ---------------------------------------------------------------------------
// fp32 -> bf16 conversion (4 elems/thread)
// ---------------------------------------------------------------------------
__global__ __launch_bounds__(256) void cvt_bf16(const float* __restrict__ in,
                                                unsigned short* __restrict__ out,
                                                int n4) {
  int i = blockIdx.x * 256 + threadIdx.x;
  if (i >= n4) return;
  float4 v = ((const float4*)in)[i];
  ushort4 o;
  o.x = f2bf(v.x); o.y = f2bf(v.y); o.z = f2bf(v.z); o.w = f2bf(v.w);
  ((ushort4*)out)[i] = o;
}

// ---------------------------------------------------------------------------
// bf16 MFMA GEMM NT (128x128 tile, BK=64, 4 waves): used for QKV (mode 1)
// and MLP1 (mode 2, bf16 C + relu).
// mode 1: QKV routing, all bf16: col<512 -> Cb q (scaled 1/8, [row][512]);
//         col<1024 -> kb [b][pos][512]; else -> vt [b][h][d][CAP] (V^T).
// ---------------------------------------------------------------------------
__global__ __launch_bounds__(256) void mfma_gemm(
    const unsigned short* __restrict__ A, const unsigned short* __restrict__ Bw,
    const float* __restrict__ bias,
    unsigned short* __restrict__ Cb,
    unsigned short* __restrict__ kb, unsigned short* __restrict__ vt,
    int M, int N, int K, int mode, int relu)
{
  __shared__ unsigned short Als[128 * 64];
  __shared__ unsigned short Bls[128 * 64];
  const int tid  = threadIdx.x;
  const int lane = tid & 63, w = tid >> 6;
  const int bm = blockIdx.x * 128, bn = blockIdx.y * 128;
  const int wm = (w >> 1) * 64, wn = (w & 1) * 64;

  f32x4 acc[4][4] = {};

  const int so = tid * 16;
  for (int k0 = 0; k0 < K; k0 += 64) {
#pragma unroll
    for (int it = 0; it < 4; ++it) {
      int o   = it * 4096 + so;
      int row = o >> 7;             // 128 B per LDS row (64 bf16)
      int ch  = (o >> 4) & 7;
      int sch = ch ^ (row & 7);     // inverse-swizzled global source
      async16(A  + (size_t)(bm + row) * K + k0 + sch * 8, (char*)Als + o);
      async16(Bw + (size_t)(bn + row) * K + k0 + sch * 8, (char*)Bls + o);
    }
    __syncthreads();
#pragma unroll
    for (int ks = 0; ks < 2; ++ks) {
      bf8 af[4], bfr[4];
#pragma unroll
      for (int m = 0; m < 4; ++m) {
        int row = wm + m * 16 + (lane & 15);
        int ch  = ks * 4 + (lane >> 4);
        af[m] = *(const bf8*)((const char*)Als + row * 128 + ((ch ^ (row & 7)) * 16));
      }
#pragma unroll
      for (int n = 0; n < 4; ++n) {
        int row = wn + n * 16 + (lane & 15);
        int ch  = ks * 4 + (lane >> 4);
        bfr[n] = *(const bf8*)((const char*)Bls + row * 128 + ((ch ^ (row & 7)) * 16));
      }
#pragma unroll
      for (int m = 0; m < 4; ++m)
#pragma unroll
        for (int n = 0; n < 4; ++n)
          acc[m][n] = __builtin_amdgcn_mfma_f32_16x16x32_bf16(af[m], bfr[n], acc[m][n], 0, 0, 0);
    }
    __syncthreads();
  }

#pragma unroll
  for (int m = 0; m < 4; ++m) {
#pragma unroll
    for (int n = 0; n < 4; ++n) {
      int col  = bn + wn + n * 16 + (lane & 15);
      int row0 = bm + wm + m * 16 + ((lane >> 4) << 2);
      float bcol = bias[col];
      if (mode == 1) {
        if (col < 512) {
#pragma unroll
          for (int r = 0; r < 4; ++r)
            Cb[((size_t)(row0 + r) << 9) + col] = f2bf((acc[m][n][r] + bcol) * 0.125f);
        } else if (col < 1024) {
#pragma unroll
          for (int r = 0; r < 4; ++r) {
            int row = row0 + r; int bb, pos;
            if (row < 8192) { bb = row >> 10; pos = row & 1023; }
            else { int r2 = row - 8192; bb = r2 & 7; pos = 1024 + (r2 >> 3); }
            kb[(((size_t)(bb * CAP_ + pos)) << 9) + (col - 512)] = f2bf(acc[m][n][r] + bcol);
          }
        } else {
          int c = col - 1024; int hh = c >> 6, d = c & 63;
          if (row0 < 8192) {        // 4 consecutive pos within one b
            int bb = row0 >> 10, pos = row0 & 1023;
            ushort4 pk;
            pk.x = f2bf(acc[m][n][0] + bcol); pk.y = f2bf(acc[m][n][1] + bcol);
            pk.z = f2bf(acc[m][n][2] + bcol); pk.w = f2bf(acc[m][n][3] + bcol);
            *(ushort4*)(vt + ((size_t)((bb * 8 + hh) * 64 + d)) * CAP_ + pos) = pk;
          } else {
#pragma unroll
            for (int r = 0; r < 4; ++r) {
              int r2 = row0 + r - 8192; int bb = r2 & 7, pos = 1024 + (r2 >> 3);
              vt[((size_t)((bb * 8 + hh) * 64 + d)) * CAP_ + pos] = f2bf(acc[m][n][r] + bcol);
            }
          }
        }
      } else {
#pragma unroll
        for (int r = 0; r < 4; ++r) {
          float v = acc[m][n][r] + bcol;
          if (relu) v = fmaxf(v, 0.f);
          Cb[(size_t)(row0 + r) * N + col] = f2bf(v);
        }
      }
    }
  }
}

// ---------------------------------------------------------------------------
// Full-row fused GEMM + residual + LayerNorm for N=512 outputs.
// C[row, 0..511] = A[row,:]*Bw^T + bias + res; then LN over the 512 cols.
// Tile: 32 rows x 512 cols, 4 waves (wave w owns cols w*128..+128).
// B staged in 64KB swizzled LDS via global_load_lds; A frags loaded from
// global with next-iter prefetch. Epilogue: in-block LN (shfl + cross-wave
// LDS reduce, reusing Bls).
// mode 0: write bf16 outb[row*512+col] (proj+LN1 -> h1_bf)
// mode 1: write fp32 outf routed (b,s) (MLP2+LN2 -> d_out)
// ---------------------------------------------------------------------------
__global__ __launch_bounds__(256) void gemm_fullrow_ln(
    const unsigned short* __restrict__ A,     // [8704][K]
    const unsigned short* __restrict__ Bw,    // [512][K]
    const float* __restrict__ bias,           // [512]
    const unsigned short* __restrict__ resb,  // [8704][512] bf16
    const float* __restrict__ lnw, const float* __restrict__ lnb,
    unsigned short* __restrict__ outb, float* __restrict__ outf,
    int K, int mode)
{
  __shared__ unsigned short Bls[512 * 64];    // 64 KB, reused for LN reduce
  const int tid = threadIdx.x, lane = tid & 63, w = tid >> 6;
  const int l4 = lane >> 4, l15 = lane & 15;
  const int bm = blockIdx.x * 32;

  f32x4 acc[2][8] = {};
  bf8 a_cur[2][2], a_nxt[2][2];

#pragma unroll
  for (int ks = 0; ks < 2; ++ks)
#pragma unroll
    for (int mf = 0; mf < 2; ++mf)
      a_cur[ks][mf] = *(const bf8*)(A + (size_t)(bm + mf * 16 + l15) * K + (ks * 4 + l4) * 8);

  for (int k0 = 0; k0 < K; k0 += 64) {
#pragma unroll
    for (int it = 0; it < 16; ++it) {
      int o   = it * 4096 + tid * 16;
      int row = o >> 7;                       // 0..511 (B row = out col)
      int sch = ((o >> 4) & 7) ^ (row & 7);
      async16(Bw + (size_t)row * K + k0 + sch * 8, (char*)Bls + o);
    }
    if (k0 + 64 < K) {
#pragma unroll
      for (int ks = 0; ks < 2; ++ks)
#pragma unroll
        for (int mf = 0; mf < 2; ++mf)
          a_nxt[ks][mf] = *(const bf8*)(A + (size_t)(bm + mf * 16 + l15) * K +
                                        k0 + 64 + (ks * 4 + l4) * 8);
    }
    __syncthreads();                          // B staged (vmcnt drained)
#pragma unroll
    for (int ks = 0; ks < 2; ++ks) {
      int cb = ks * 4 + l4;
#pragma unroll
      for (int nf = 0; nf < 8; ++nf) {
        int row = w * 128 + nf * 16 + l15;
        bf8 bfv = *(const bf8*)((const char*)Bls + row * 128 + ((cb ^ (row & 7)) << 4));
#pragma unroll
        for (int mf = 0; mf < 2; ++mf)
          acc[mf][nf] = __builtin_amdgcn_mfma_f32_16x16x32_bf16(a_cur[ks][mf], bfv, acc[mf][nf], 0, 0, 0);
      }
    }
#pragma unroll
    for (int ks = 0; ks < 2; ++ks)
#pragma unroll
      for (int mf = 0; mf < 2; ++mf)
        a_cur[ks][mf] = a_nxt[ks][mf];
    __syncthreads();                          // B reads done before restage
  }

  // ---- epilogue: bias + residual, then LN over the full 512-col row ----
  float bc[8], lw[8], lb[8];
#pragma unroll
  for (int nf = 0; nf < 8; ++nf) {
    int col = w * 128 + nf * 16 + l15;
    bc[nf] = bias[col]; lw[nf] = lnw[col]; lb[nf] = lnb[col];
  }
#pragma unroll
  for (int nf = 0; nf < 8; ++nf) {
    int col = w * 128 + nf * 16 + l15;
#pragma unroll
    for (int mf = 0; mf < 2; ++mf)
#pragma unroll
      for (int r = 0; r < 4; ++r) {
        int rowg = bm + mf * 16 + l4 * 4 + r;
        acc[mf][nf][r] += bc[nf] + bf2f(resb[(size_t)rowg * 512 + col]);
      }
  }

  float* red = (float*)Bls;                   // [32 rows][4 waves][2]
#pragma unroll
  for (int mf = 0; mf < 2; ++mf)
#pragma unroll
    for (int r = 0; r < 4; ++r) {
      float s = 0.f, q = 0.f;
#pragma unroll
      for (int nf = 0; nf < 8; ++nf) { float v = acc[mf][nf][r]; s += v; q += v * v; }
#pragma unroll
      for (int off = 1; off < 16; off <<= 1) {
        s += __shfl_xor(s, off, 64); q += __shfl_xor(q, off, 64);
      }
      if (l15 == 0) {
        int rl = mf * 16 + l4 * 4 + r;
        red[rl * 8 + w * 2]     = s;
        red[rl * 8 + w * 2 + 1] = q;
      }
    }
  __syncthreads();

#pragma unroll
  for (int mf = 0; mf < 2; ++mf)
#pragma unroll
    for (int r = 0; r < 4; ++r) {
      int rl = mf * 16 + l4 * 4 + r;
      float S = red[rl * 8 + 0] + red[rl * 8 + 2] + red[rl * 8 + 4] + red[rl * 8 + 6];
      float Q = red[rl * 8 + 1] + red[rl * 8 + 3] + red[rl * 8 + 5] + red[rl * 8 + 7];
      float mu  = S * (1.f / 512.f);
      float var = Q * (1.f / 512.f) - mu * mu;
      float inv = rsqrtf(var + EPS_);
      int rowg = bm + rl;
      if (mode == 0) {
#pragma unroll
        for (int nf = 0; nf < 8; ++nf) {
          int col = w * 128 + nf * 16 + l15;
          float y = (acc[mf][nf][r] - mu) * inv * lw[nf] + lb[nf];
          outb[(size_t)rowg * 512 + col] = f2bf(y);
        }
      } else {
        int b, s2;
        if (rowg < 8192) { b = rowg >> 10; s2 = rowg & 1023; }
        else { int r2 = rowg - 8192; b = r2 & 7; s2 = 1024 + (r2 >> 3); }
        size_t ob = ((size_t)(b * CAP_ + s2)) << 9;
#pragma unroll
        for (int nf = 0; nf < 8; ++nf) {
          int col = w * 128 + nf * 16 + l15;
          outf[ob + col] = (acc[mf][nf][r] - mu) * inv * lw[nf] + lb[nf];
        }
      }
    }
}

// ---------------------------------------------------------------------------
// MFMA attention (unchanged from round 5). grid (17,64).
// ---------------------------------------------------------------------------
__global__ __launch_bounds__(256) void attn_mfma(
    const unsigned short* __restrict__ qb,   // [8704][512], pre-scaled 1/8
    const unsigned short* __restrict__ kcb,  // [8][1088][512]
    const unsigned short* __restrict__ vtb,  // [8][8][64][1088]
    unsigned short* __restrict__ ob)         // [8704][512]
{
  __shared__ unsigned short Kls[4096];
  __shared__ unsigned short Vls[4096];
  __shared__ unsigned short Pls[4096];
  const int st = blockIdx.x, bh = blockIdx.y;
  const int b = bh >> 3, h = bh & 7;
  const bool dec = (st == 16);
  const int tid = threadIdx.x, lane = tid & 63, w = tid >> 6;
  const int wq = w * 16;
  const int nT = dec ? 17 : st + 1;
  const int qi = wq + (lane & 15);
  const size_t g = dec ? (size_t)(8192 + qi * 8 + b)
                       : (size_t)((b << 10) + st * 64 + qi);

  const bf8 qf0 = *(const bf8*)(qb + (g << 9) + h * 64 +      ((lane >> 4) << 3));
  const bf8 qf1 = *(const bf8*)(qb + (g << 9) + h * 64 + 32 + ((lane >> 4) << 3));

  f32x4 oo[4] = {};
  float m_ = -1e30f, l_ = 0.f;

  const size_t kbase = (((size_t)b * CAP_) << 9) + h * 64;
  const size_t vbase = (size_t)((b * 8 + h) * 64) * CAP_;

  for (int t = 0; t < nT; ++t) {
    const int t0 = t * 64;
    __syncthreads();
#pragma unroll
    for (int it = 0; it < 2; ++it) {
      int o   = it * 4096 + tid * 16;
      int row = o >> 7;
      int sch = ((o >> 4) & 7) ^ (row & 7);
      async16(kcb + kbase + (((size_t)(t0 + row)) << 9) + sch * 8, (char*)Kls + o);
      async16(vtb + vbase + (size_t)row * CAP_ + t0 + sch * 8,     (char*)Vls + o);
    }
    __syncthreads();

    f32x4 sfr[4] = {};
#pragma unroll
    for (int ks = 0; ks < 2; ++ks) {
      int cb = ks * 4 + (lane >> 4);
      bf8 qv = ks ? qf1 : qf0;
#pragma unroll
      for (int f = 0; f < 4; ++f) {
        int row = f * 16 + (lane & 15);
        bf8 kf = *(const bf8*)((const char*)Kls + row * 128 + ((cb ^ (row & 7)) << 4));
        sfr[f] = __builtin_amdgcn_mfma_f32_16x16x32_bf16(kf, qv, sfr[f], 0, 0, 0);
      }
    }
    if (t == nT - 1) {
#pragma unroll
      for (int f = 0; f < 4; ++f)
#pragma unroll
        for (int r = 0; r < 4; ++r) {
          int tr = f * 16 + ((lane >> 4) << 2) + r;
          if (tr > qi) sfr[f][r] = -1e30f;
        }
    }

    float pmax = -1e30f;
#pragma unroll
    for (int f = 0; f < 4; ++f)
#pragma unroll
      for (int r = 0; r < 4; ++r) pmax = fmaxf(pmax, sfr[f][r]);
    pmax = fmaxf(pmax, __shfl_xor(pmax, 16, 64));
    pmax = fmaxf(pmax, __shfl_xor(pmax, 32, 64));
    float mn  = fmaxf(m_, pmax);
    float fsc = __expf(m_ - mn);
    float rs = 0.f;
#pragma unroll
    for (int f = 0; f < 4; ++f)
#pragma unroll
      for (int r = 0; r < 4; ++r) {
        float e = __expf(sfr[f][r] - mn);
        sfr[f][r] = e; rs += e;
      }
    rs += __shfl_xor(rs, 16, 64);
    rs += __shfl_xor(rs, 32, 64);
    l_ = l_ * fsc + rs; m_ = mn;
#pragma unroll
    for (int f = 0; f < 4; ++f) oo[f] *= fsc;

#pragma unroll
    for (int f = 0; f < 4; ++f) {
      ushort4 pk;
      pk.x = f2bf(sfr[f][0]); pk.y = f2bf(sfr[f][1]);
      pk.z = f2bf(sfr[f][2]); pk.w = f2bf(sfr[f][3]);
      int tb   = f * 32 + ((lane >> 4) << 3);
      int addr = qi * 128 + ((((tb >> 4)) ^ (qi & 7)) << 4) + (tb & 15);
      *(ushort4*)((char*)Pls + addr) = pk;
    }
    __syncthreads();

#pragma unroll
    for (int ks = 0; ks < 2; ++ks) {
      int cb = ks * 4 + (lane >> 4);
      bf8 pf = *(const bf8*)((const char*)Pls + qi * 128 + ((cb ^ (qi & 7)) << 4));
#pragma unroll
      for (int f = 0; f < 4; ++f) {
        int row = f * 16 + (lane & 15);
        bf8 vf = *(const bf8*)((const char*)Vls + row * 128 + ((cb ^ (row & 7)) << 4));
        oo[f] = __builtin_amdgcn_mfma_f32_16x16x32_bf16(vf, pf, oo[f], 0, 0, 0);
      }
    }
  }

  const float inv = 1.f / l_;
#pragma unroll
  for (int f = 0; f < 4; ++f) {
    ushort4 pk;
    pk.x = f2bf(oo[f][0] * inv); pk.y = f2bf(oo[f][1] * inv);
    pk.z = f2bf(oo[f][2] * inv); pk.w = f2bf(oo[f][3] * inv);
    int d0 = f * 16 + ((lane >> 4) << 2);
    *(ushort4*)(ob + (g << 9) + h * 64 + d0) = pk;
  }
}

// ---------------------------------------------------------------------------
extern "C" void kernel_launch(void* const* d_in, const int* in_sizes, int n_in,
                              void* d_out, int out_size, void* d_ws, size_t ws_size,
                              hipStream_t stream)
{
  const float* x     = (const float*)d_in[0];
  const float* dx    = (const float*)d_in[1];   // [64,8,1,512] rows t*8+b
  const float* qkv_w = (const float*)d_in[3];
  const float* qkv_b = (const float*)d_in[4];
  const float* out_w = (const float*)d_in[5];
  const float* out_b = (const float*)d_in[6];
  const float* w1    = (const float*)d_in[7];
  const float* b1    = (const float*)d_in[8];
  const float* w2    = (const float*)d_in[9];
  const float* b2    = (const float*)d_in[10];
  const float* ln1w  = (const float*)d_in[11];
  const float* ln1b  = (const float*)d_in[12];
  const float* ln2w  = (const float*)d_in[13];
  const float* ln2b  = (const float*)d_in[14];
  float* out = (float*)d_out;

  // M = 8704 rows: 8192 prefill tokens + 512 decode tokens (row 8192 + t*8+b)
  float* ws = (float*)d_ws;
  size_t o = 0;
  unsigned short* x_bf    = (unsigned short*)(ws + o); o += (size_t)8704 * 256;
  unsigned short* qkvw_bf = (unsigned short*)(ws + o); o += 1536 * 256;
  unsigned short* outw_bf = (unsigned short*)(ws + o); o += 512 * 256;
  unsigned short* w1_bf   = (unsigned short*)(ws + o); o += 2048 * 256;
  unsigned short* w2_bf   = (unsigned short*)(ws + o); o += (size_t)512 * 1024;
  unsigned short* qb_bf   = (unsigned short*)(ws + o); o += (size_t)8704 * 256;
  unsigned short* kcb     = (unsigned short*)(ws + o); o += (size_t)8 * CAP_ * 256;
  unsigned short* vtb     = (unsigned short*)(ws + o); o += (size_t)8 * 512 * CAP_ / 2;
  unsigned short* attn_bf = (unsigned short*)(ws + o); o += (size_t)8704 * 256;
  unsigned short* h1_bf   = (unsigned short*)(ws + o); o += (size_t)8704 * 256;
  unsigned short* hid_bf  = (unsigned short*)(ws + o); o += (size_t)8704 * 1024;

  // ---- conversions ----
  cvt_bf16<<<dim3(4096), 256, 0, stream>>>(x,  x_bf,                      1048576);
  cvt_bf16<<<dim3(256),  256, 0, stream>>>(dx, x_bf + (size_t)8192 * 512, 65536);
  cvt_bf16<<<dim3(768),  256, 0, stream>>>(qkv_w, qkvw_bf, 196608);
  cvt_bf16<<<dim3(256),  256, 0, stream>>>(out_w, outw_bf, 65536);
  cvt_bf16<<<dim3(1024), 256, 0, stream>>>(w1,    w1_bf,   262144);
  cvt_bf16<<<dim3(1024), 256, 0, stream>>>(w2,    w2_bf,   262144);

  // ---- QKV (prefill + all decode steps), outputs bf16 q / K-cache / V^T ----
  mfma_gemm<<<dim3(68, 12), 256, 0, stream>>>(x_bf, qkvw_bf, qkv_b,
      qb_bf, kcb, vtb, 8704, 1536, 512, 1, 0);
  // ---- attention: prefill tiles 0..15 + decode tile 16 ----
  attn_mfma<<<dim3(17, 64), 256, 0, stream>>>(qb_bf, kcb, vtb, attn_bf);
  // ---- out-proj + residual(x_bf) + LN1, fused -> h1_bf ----
  gemm_fullrow_ln<<<dim3(272), 256, 0, stream>>>(attn_bf, outw_bf, out_b,
      x_bf, ln1w, ln1b, h1_bf, nullptr, 512, 0);
  // ---- MLP1 (relu, bf16 out) ----
  mfma_gemm<<<dim3(68, 16), 256, 0, stream>>>(h1_bf, w1_bf, b1,
      hid_bf, nullptr, nullptr, 8704, 2048, 512, 2, 1);
  // ---- MLP2 + residual(h1_bf) + LN2, fused -> routed fp32 d_out ----
  gemm_fullrow_ln<<<dim3(272), 256, 0, stream>>>(hid_bf, w2_bf, b2,
      h1_bf, ln2w, ln2b, nullptr, out, 2048, 1);
}